// Round 8
// baseline (1281.039 us; speedup 1.0000x reference)
//
#include <hip/hip_runtime.h>
#include <math.h>

#define TT   512
#define BB   64
#define EMBD 512
#define HIDD 512

typedef _Float16 half2v __attribute__((ext_vector_type(2)));

__device__ __forceinline__ float fdot2(unsigned a, unsigned b, float c) {
  half2v av = __builtin_bit_cast(half2v, a);
  half2v bv = __builtin_bit_cast(half2v, b);
#if __has_builtin(__builtin_amdgcn_fdot2)
  return __builtin_amdgcn_fdot2(av, bv, c, false);
#else
  return c + (float)av.x * (float)bv.x + (float)av.y * (float)bv.y;
#endif
}

__device__ __forceinline__ float fast_tanh(float x) {
  float e = __expf(2.0f * x);
  return 1.0f - 2.0f * __builtin_amdgcn_rcpf(e + 1.0f);
}

__device__ __forceinline__ unsigned pack2(float a, float b) {
  half2v hv; hv.x = (_Float16)a; hv.y = (_Float16)b;
  return __builtin_bit_cast(unsigned, hv);
}

// ---------------------------------------------------------------------------
// K0: repack fp32 W1h -> fp16 chunks for the v8 mapping.
// elman thread tid: w=tid>>6, l=tid&63, kh=l>>3, jo=l&7.
// chunk c (0..63): s=c>>3, i=c&7. Covers j=64w+8jo+s, k=64kh+8i..+8,
// packed as 4 dwords of (even,odd) fp16 pairs. wp[c*512+tid].
// ---------------------------------------------------------------------------
__global__ __launch_bounds__(256) void repack_w1h(
    const float* __restrict__ W1, uint4* __restrict__ wp)
{
  const int gid = blockIdx.x * 256 + threadIdx.x;   // 0..32767
  const int c   = gid >> 9;
  const int tid = gid & 511;
  const int w = tid >> 6, l = tid & 63;
  const int kh = l >> 3, jo = l & 7;
  const int s = c >> 3, i = c & 7;
  const int j  = 64 * w + 8 * jo + s;
  const int k0 = 64 * kh + 8 * i;
  const float* src = W1 + (size_t)j * (2 * EMBD) + EMBD + k0;
  unsigned r[4];
#pragma unroll
  for (int q = 0; q < 4; q++) r[q] = pack2(src[2 * q], src[2 * q + 1]);
  uint4 u; u.x = r[0]; u.y = r[1]; u.z = r[2]; u.w = r[3];
  wp[gid] = u;
}

// ---------------------------------------------------------------------------
// K1: px[m][j] = b1[j] + sum_k emb[x[m]][k] * W1[j][k]  (fp32 tile GEMM)
// ---------------------------------------------------------------------------
__global__ __launch_bounds__(256) void px_gemm(
    const int* __restrict__ x, const float* __restrict__ emb,
    const float* __restrict__ W1, const float* __restrict__ b1,
    float* __restrict__ px)
{
  __shared__ float As[8][132];
  __shared__ float Bs[8][132];
  __shared__ int stok[128];
  const int tid = threadIdx.x;
  const int m0 = blockIdx.x * 128;
  const int j0 = blockIdx.y * 128;
  if (tid < 128) stok[tid] = x[m0 + tid];
  __syncthreads();
  const int lr = tid >> 1;
  const int lh = (tid & 1) * 4;
  const int ty = tid >> 4, tx = tid & 15;
  const size_t arow = (size_t)stok[lr] * EMBD;
  const float* brow = W1 + (size_t)(j0 + lr) * (2 * EMBD);

  float acc[8][8];
#pragma unroll
  for (int i = 0; i < 8; i++)
#pragma unroll
    for (int q = 0; q < 8; q++) acc[i][q] = 0.f;

  for (int k0 = 0; k0 < EMBD; k0 += 8) {
    float4 av = *(const float4*)(emb + arow + k0 + lh);
    float4 bv = *(const float4*)(brow + k0 + lh);
    __syncthreads();
    As[lh + 0][lr] = av.x; As[lh + 1][lr] = av.y; As[lh + 2][lr] = av.z; As[lh + 3][lr] = av.w;
    Bs[lh + 0][lr] = bv.x; Bs[lh + 1][lr] = bv.y; Bs[lh + 2][lr] = bv.z; Bs[lh + 3][lr] = bv.w;
    __syncthreads();
#pragma unroll
    for (int kk = 0; kk < 8; kk++) {
      float4 a0 = *(const float4*)&As[kk][ty * 8];
      float4 a1 = *(const float4*)&As[kk][ty * 8 + 4];
      float4 c0 = *(const float4*)&Bs[kk][tx * 8];
      float4 c1 = *(const float4*)&Bs[kk][tx * 8 + 4];
      float a[8] = {a0.x,a0.y,a0.z,a0.w,a1.x,a1.y,a1.z,a1.w};
      float bb[8] = {c0.x,c0.y,c0.z,c0.w,c1.x,c1.y,c1.z,c1.w};
#pragma unroll
      for (int i = 0; i < 8; i++)
#pragma unroll
        for (int q = 0; q < 8; q++)
          acc[i][q] = fmaf(a[i], bb[q], acc[i][q]);
    }
  }
  const float* bp = b1 + j0 + tx * 8;
  float bias0[8];
#pragma unroll
  for (int q = 0; q < 8; q++) bias0[q] = bp[q];
#pragma unroll
  for (int i = 0; i < 8; i++) {
    float o[8];
#pragma unroll
    for (int q = 0; q < 8; q++) o[q] = acc[i][q] + bias0[q];
    float* dst = px + (size_t)(m0 + ty * 8 + i) * HIDD + j0 + tx * 8;
    *(float4*)dst       = make_float4(o[0], o[1], o[2], o[3]);
    *(float4*)(dst + 4) = make_float4(o[4], o[5], o[6], o[7]);
  }
}

// ---------------------------------------------------------------------------
// K2: recurrence v8. 64 wgs x 512 thr (8 waves, 2/SIMD). Lane l: kh=l>>3,
// jo=l&7. Thread: 8 j (64w+8jo+s) x 64 k ([64kh,64kh+64)).
// h-reads per step: 8 x b128 (vs 16 in r6); weight chunks: 48 reg +
// 7 static LDS + 7 dynamic LDS + 2 streamed from L2.
// h chunk logical p=i*8+kh, phys = (p>>3)*8 + ((p&7)^(p>>3)): broadcast
// reads AND the 8-writer stores both hit 32 distinct banks.
// Merge: 3-level shfl_xor butterfly. One barrier/step.
// ---------------------------------------------------------------------------
#define DOTQ(ACC, WW, HH)                                                   \
    ACC = fdot2((WW).x, (HH).x, ACC); ACC = fdot2((WW).y, (HH).y, ACC);     \
    ACC = fdot2((WW).z, (HH).z, ACC); ACC = fdot2((WW).w, (HH).w, ACC);

#define STEPI(I, W6, W7) {                                                  \
    const uint4 hh = hq[(I) * 8 + (kh ^ (I))];                              \
    DOTQ(a0, wr[ 0 + (I)], hh)  DOTQ(a1, wr[ 8 + (I)], hh)                  \
    DOTQ(a2, wr[16 + (I)], hh)  DOTQ(a3, wr[24 + (I)], hh)                  \
    DOTQ(a4, wr[32 + (I)], hh)  DOTQ(a5, wr[40 + (I)], hh)                  \
    DOTQ(a6, (W6), hh)          DOTQ(a7, (W7), hh)                          \
  }

__attribute__((amdgpu_flat_work_group_size(512, 512), amdgpu_waves_per_eu(2)))
__global__ void elman_v8(
    const uint4* __restrict__ wp, const float* __restrict__ px,
    const float* __restrict__ W2, const float* __restrict__ b2,
    float* __restrict__ out)
{
  extern __shared__ uint4 wdyn[];      // 7*512 uint4 = 56 KB (c 57..63)
  __shared__ uint4 wstat[7 * 512];     // 56 KB (c 50..56)
  __shared__ uint4 h2[2][64];          // packed fp16 h, dbuf, swizzled
  __shared__ float red[2][8];

  const int b   = blockIdx.x;
  const int tid = threadIdx.x;
  const int w   = tid >> 6, l = tid & 63;
  const int kh  = l >> 3, jo = l & 7;

  // prologue: 48 reg chunks (c 0..47) + 14 LDS chunks (all coalesced)
  uint4 wr[48];
#pragma unroll
  for (int i = 0; i < 48; i++) wr[i] = wp[(size_t)i * 512 + tid];
#pragma unroll
  for (int i = 0; i < 7; i++) wstat[i * 512 + tid] = wp[(size_t)(50 + i) * 512 + tid];
#pragma unroll
  for (int i = 0; i < 7; i++) wdyn[i * 512 + tid] = wp[(size_t)(57 + i) * 512 + tid];
  if (tid < 64) {
    uint4 z; z.x = z.y = z.z = z.w = 0u;
    h2[0][tid] = z;
  }
  __syncthreads();

  const uint4* wsrc = wp + (size_t)48 * 512 + tid;   // c 48, 49 (streamed)
  const float* pxp  = px + (size_t)b * TT * HIDD + 64 * w + 8 * jo;
  float rm0 = -INFINITY, rm1 = -INFINITY, rm2 = -INFINITY, rm3 = -INFINITY;
  float rm4 = -INFINITY, rm5 = -INFINITY, rm6 = -INFINITY, rm7 = -INFINITY;

  for (int t = 0; t < TT; t++) {
    const int cur = t & 1;

    // early issues: px (writer lanes) + the 2 streamed chunks
    float4 pxa = make_float4(0.f, 0.f, 0.f, 0.f);
    float4 pxb = make_float4(0.f, 0.f, 0.f, 0.f);
    if (l < 8) {
      pxa = *(const float4*)(pxp + (size_t)t * HIDD);
      pxb = *(const float4*)(pxp + (size_t)t * HIDD + 4);
    }
    const uint4 s0 = wsrc[0];
    const uint4 s1 = wsrc[512];

    const uint4* hq = &h2[cur][0];
    float a0 = 0.f, a1 = 0.f, a2 = 0.f, a3 = 0.f;
    float a4 = 0.f, a5 = 0.f, a6 = 0.f, a7 = 0.f;

    // c = s*8+i. s6: i0->s0, i1->s1, i>=2->wstat[i-2]. s7: i0->wstat[6], i>=1->wdyn[i-1].
    STEPI(0, s0,                   wstat[6 * 512 + tid])
    STEPI(1, s1,                   wdyn [0 * 512 + tid])
    STEPI(2, wstat[0 * 512 + tid], wdyn [1 * 512 + tid])
    STEPI(3, wstat[1 * 512 + tid], wdyn [2 * 512 + tid])
    STEPI(4, wstat[2 * 512 + tid], wdyn [3 * 512 + tid])
    STEPI(5, wstat[3 * 512 + tid], wdyn [4 * 512 + tid])
    STEPI(6, wstat[4 * 512 + tid], wdyn [5 * 512 + tid])
    STEPI(7, wstat[5 * 512 + tid], wdyn [6 * 512 + tid])

    // butterfly over kh (lane bits 3..5): every lane ends with full sums
    a0 += __shfl_xor(a0, 8);  a1 += __shfl_xor(a1, 8);
    a2 += __shfl_xor(a2, 8);  a3 += __shfl_xor(a3, 8);
    a4 += __shfl_xor(a4, 8);  a5 += __shfl_xor(a5, 8);
    a6 += __shfl_xor(a6, 8);  a7 += __shfl_xor(a7, 8);
    a0 += __shfl_xor(a0, 16); a1 += __shfl_xor(a1, 16);
    a2 += __shfl_xor(a2, 16); a3 += __shfl_xor(a3, 16);
    a4 += __shfl_xor(a4, 16); a5 += __shfl_xor(a5, 16);
    a6 += __shfl_xor(a6, 16); a7 += __shfl_xor(a7, 16);
    a0 += __shfl_xor(a0, 32); a1 += __shfl_xor(a1, 32);
    a2 += __shfl_xor(a2, 32); a3 += __shfl_xor(a3, 32);
    a4 += __shfl_xor(a4, 32); a5 += __shfl_xor(a5, 32);
    a6 += __shfl_xor(a6, 32); a7 += __shfl_xor(a7, 32);

    if (l < 8) {                      // writer lanes: jo = l, kh = 0
      float h0 = fast_tanh(a0 + pxa.x);
      float h1 = fast_tanh(a1 + pxa.y);
      float h2v = fast_tanh(a2 + pxa.z);
      float h3 = fast_tanh(a3 + pxa.w);
      float h4 = fast_tanh(a4 + pxb.x);
      float h5 = fast_tanh(a5 + pxb.y);
      float h6 = fast_tanh(a6 + pxb.z);
      float h7 = fast_tanh(a7 + pxb.w);
      rm0 = fmaxf(rm0, h0); rm1 = fmaxf(rm1, h1);
      rm2 = fmaxf(rm2, h2v); rm3 = fmaxf(rm3, h3);
      rm4 = fmaxf(rm4, h4); rm5 = fmaxf(rm5, h5);
      rm6 = fmaxf(rm6, h6); rm7 = fmaxf(rm7, h7);
      uint4 hv;
      hv.x = pack2(h0, h1);  hv.y = pack2(h2v, h3);
      hv.z = pack2(h4, h5);  hv.w = pack2(h6, h7);
      h2[cur ^ 1][jo * 8 + (w ^ jo)] = hv;   // swizzled: banks distinct
      if (t == TT - 1) {
        float* dst = out + 2 * BB + (size_t)b * HIDD + 64 * w + 8 * jo;
        *(float4*)dst       = make_float4(h0, h1, h2v, h3);
        *(float4*)(dst + 4) = make_float4(h4, h5, h6, h7);
      }
    }
    __syncthreads();
  }

  // pooled max -> logits (pl overlays dynamic weight LDS; weights dead now)
  float* pl = (float*)wdyn;
  if (l < 8) {
    *(float4*)&pl[64 * w + 8 * jo]     = make_float4(rm0, rm1, rm2, rm3);
    *(float4*)&pl[64 * w + 8 * jo + 4] = make_float4(rm4, rm5, rm6, rm7);
  }
  __syncthreads();
  {
    float pv = pl[tid];
    float q0 = pv * W2[tid];
    float q1 = pv * W2[HIDD + tid];
#pragma unroll
    for (int off = 32; off; off >>= 1) {
      q0 += __shfl_down(q0, off);
      q1 += __shfl_down(q1, off);
    }
    const int wv = tid >> 6, ln = tid & 63;
    if (ln == 0) { red[0][wv] = q0; red[1][wv] = q1; }
  }
  __syncthreads();
  if (tid < 2) {
    float s = b2[tid];
#pragma unroll
    for (int i = 0; i < 8; i++) s += red[tid][i];
    out[b * 2 + tid] = s;
  }
}

// ---------------------------------------------------------------------------
extern "C" void kernel_launch(void* const* d_in, const int* in_sizes, int n_in,
                              void* d_out, int out_size, void* d_ws, size_t ws_size,
                              hipStream_t stream)
{
  const int*   x   = (const int*)d_in[0];
  const float* emb = (const float*)d_in[1];
  const float* W1  = (const float*)d_in[2];
  const float* b1  = (const float*)d_in[3];
  const float* W2  = (const float*)d_in[4];
  const float* b2  = (const float*)d_in[5];
  float* out = (float*)d_out;
  char* ws = (char*)d_ws;

  uint4* wp = (uint4*)ws;                        // 512 KB repacked fp16 W1h
  float* px = (float*)(ws + (1 << 19));          // 64 MB
  const size_t need = (size_t)(1 << 19) + (size_t)BB * TT * HIDD * sizeof(float);
  if (ws_size < need) return;

  repack_w1h<<<128, 256, 0, stream>>>(W1, wp);
  {
    dim3 g(TT * BB / 128, HIDD / 128);           // (256, 4)
    px_gemm<<<g, 256, 0, stream>>>(x, emb, W1, b1, px);
  }

  const size_t dynBytes = (size_t)7 * 512 * sizeof(uint4);   // 57344 B
  elman_v8<<<dim3(BB), dim3(512), dynBytes, stream>>>(wp, px, W2, b2, out);
}

// Round 9
// 1136.587 us; speedup vs baseline: 1.1271x; 1.1271x over previous
//
#include <hip/hip_runtime.h>
#include <math.h>

#define TT   512
#define BB   64
#define EMBD 512
#define HIDD 512

typedef _Float16 half2v __attribute__((ext_vector_type(2)));

__device__ __forceinline__ float fdot2(unsigned a, unsigned b, float c) {
  half2v av = __builtin_bit_cast(half2v, a);
  half2v bv = __builtin_bit_cast(half2v, b);
#if __has_builtin(__builtin_amdgcn_fdot2)
  return __builtin_amdgcn_fdot2(av, bv, c, false);
#else
  return c + (float)av.x * (float)bv.x + (float)av.y * (float)bv.y;
#endif
}

__device__ __forceinline__ float fast_tanh(float x) {
  float e = __expf(2.0f * x);
  return 1.0f - 2.0f * __builtin_amdgcn_rcpf(e + 1.0f);
}

__device__ __forceinline__ unsigned pack2(float a, float b) {
  half2v hv; hv.x = (_Float16)a; hv.y = (_Float16)b;
  return __builtin_bit_cast(unsigned, hv);
}

// ---------------------------------------------------------------------------
// K0: repack fp32 W1h -> fp16 chunks (r6 layout, proven).
// elman thread tid: w=tid>>6, l=tid&63, qa=l>>4, jg=l&15.
// chunk c (0..63): jo=c&3, kq=c>>2. Covers j=64w+4jg+jo, k=128qa+8kq..+8,
// packed as 4 dwords of (even,odd) fp16 pairs. wp[c*512+tid].
// ---------------------------------------------------------------------------
__global__ __launch_bounds__(256) void repack_w1h(
    const float* __restrict__ W1, uint4* __restrict__ wp)
{
  const int gid = blockIdx.x * 256 + threadIdx.x;   // 0..32767
  const int c   = gid >> 9;
  const int tid = gid & 511;
  const int w = tid >> 6, l = tid & 63;
  const int qa = l >> 4, jg = l & 15;
  const int jo = c & 3, kq = c >> 2;
  const int j  = 64 * w + 4 * jg + jo;
  const int k0 = 128 * qa + 8 * kq;
  const float* src = W1 + (size_t)j * (2 * EMBD) + EMBD + k0;
  unsigned r[4];
#pragma unroll
  for (int q = 0; q < 4; q++) r[q] = pack2(src[2 * q], src[2 * q + 1]);
  uint4 u; u.x = r[0]; u.y = r[1]; u.z = r[2]; u.w = r[3];
  wp[gid] = u;
}

// ---------------------------------------------------------------------------
// K1: px[m][j] = b1[j] + sum_k emb[x[m]][k] * W1[j][k]  (fp32 tile GEMM)
// ---------------------------------------------------------------------------
__global__ __launch_bounds__(256) void px_gemm(
    const int* __restrict__ x, const float* __restrict__ emb,
    const float* __restrict__ W1, const float* __restrict__ b1,
    float* __restrict__ px)
{
  __shared__ float As[8][132];
  __shared__ float Bs[8][132];
  __shared__ int stok[128];
  const int tid = threadIdx.x;
  const int m0 = blockIdx.x * 128;
  const int j0 = blockIdx.y * 128;
  if (tid < 128) stok[tid] = x[m0 + tid];
  __syncthreads();
  const int lr = tid >> 1;
  const int lh = (tid & 1) * 4;
  const int ty = tid >> 4, tx = tid & 15;
  const size_t arow = (size_t)stok[lr] * EMBD;
  const float* brow = W1 + (size_t)(j0 + lr) * (2 * EMBD);

  float acc[8][8];
#pragma unroll
  for (int i = 0; i < 8; i++)
#pragma unroll
    for (int q = 0; q < 8; q++) acc[i][q] = 0.f;

  for (int k0 = 0; k0 < EMBD; k0 += 8) {
    float4 av = *(const float4*)(emb + arow + k0 + lh);
    float4 bv = *(const float4*)(brow + k0 + lh);
    __syncthreads();
    As[lh + 0][lr] = av.x; As[lh + 1][lr] = av.y; As[lh + 2][lr] = av.z; As[lh + 3][lr] = av.w;
    Bs[lh + 0][lr] = bv.x; Bs[lh + 1][lr] = bv.y; Bs[lh + 2][lr] = bv.z; Bs[lh + 3][lr] = bv.w;
    __syncthreads();
#pragma unroll
    for (int kk = 0; kk < 8; kk++) {
      float4 a0 = *(const float4*)&As[kk][ty * 8];
      float4 a1 = *(const float4*)&As[kk][ty * 8 + 4];
      float4 c0 = *(const float4*)&Bs[kk][tx * 8];
      float4 c1 = *(const float4*)&Bs[kk][tx * 8 + 4];
      float a[8] = {a0.x,a0.y,a0.z,a0.w,a1.x,a1.y,a1.z,a1.w};
      float bb[8] = {c0.x,c0.y,c0.z,c0.w,c1.x,c1.y,c1.z,c1.w};
#pragma unroll
      for (int i = 0; i < 8; i++)
#pragma unroll
        for (int q = 0; q < 8; q++)
          acc[i][q] = fmaf(a[i], bb[q], acc[i][q]);
    }
  }
  const float* bp = b1 + j0 + tx * 8;
  float bias0[8];
#pragma unroll
  for (int q = 0; q < 8; q++) bias0[q] = bp[q];
#pragma unroll
  for (int i = 0; i < 8; i++) {
    float o[8];
#pragma unroll
    for (int q = 0; q < 8; q++) o[q] = acc[i][q] + bias0[q];
    float* dst = px + (size_t)(m0 + ty * 8 + i) * HIDD + j0 + tx * 8;
    *(float4*)dst       = make_float4(o[0], o[1], o[2], o[3]);
    *(float4*)(dst + 4) = make_float4(o[4], o[5], o[6], o[7]);
  }
}

// ---------------------------------------------------------------------------
// K2: recurrence v9 = r6 structure, single path. 64 wgs x 512 thr.
// Lane l: qa=l>>4 (k-quarter), jg=l&15. Thread: 4 j x 128 k during the dot;
// after the 2-level butterfly every lane holds all 4 sums and finalizes
// exactly ONE j (= 64w+4jg+qa): 1 tanh/lane, scalar px, b16 h-store.
// Weights: kq0..11 reg (48 chunks), kq12 static LDS (32KB), kq13..14
// dynamic LDS (64KB), kq15 streamed from L2 (issued first, consumed LAST).
// h chunks at p=kq*4+qa (conflict-free broadcast reads). 1 barrier/step.
// ---------------------------------------------------------------------------
#define DOT4(HH, W0, W1v, W2v, W3v) do {                                    \
    const uint4 hh = (HH);                                                  \
    a0=fdot2((W0).x,hh.x,a0);  a0=fdot2((W0).y,hh.y,a0);                    \
    a0=fdot2((W0).z,hh.z,a0);  a0=fdot2((W0).w,hh.w,a0);                    \
    a1=fdot2((W1v).x,hh.x,a1); a1=fdot2((W1v).y,hh.y,a1);                   \
    a1=fdot2((W1v).z,hh.z,a1); a1=fdot2((W1v).w,hh.w,a1);                   \
    a2=fdot2((W2v).x,hh.x,a2); a2=fdot2((W2v).y,hh.y,a2);                   \
    a2=fdot2((W2v).z,hh.z,a2); a2=fdot2((W2v).w,hh.w,a2);                   \
    a3=fdot2((W3v).x,hh.x,a3); a3=fdot2((W3v).y,hh.y,a3);                   \
    a3=fdot2((W3v).z,hh.z,a3); a3=fdot2((W3v).w,hh.w,a3);                   \
  } while (0)

__attribute__((amdgpu_flat_work_group_size(512, 512), amdgpu_waves_per_eu(2)))
__global__ void elman_v9(
    const uint4* __restrict__ wp, const float* __restrict__ px,
    const float* __restrict__ W2, const float* __restrict__ b2,
    float* __restrict__ out)
{
  extern __shared__ uint4 wdyn[];      // 8*512 uint4 = 64 KB (c 52..59)
  __shared__ uint4 wstat[4 * 512];     // 32 KB (c 48..51, = kq 12)
  __shared__ uint4 h2[2][64];          // packed fp16 h, dbuf, p = kq*4+qa
  __shared__ float red[2][8];

  const int b   = blockIdx.x;
  const int tid = threadIdx.x;
  const int w   = tid >> 6, l = tid & 63;
  const int qa  = l >> 4, jg = l & 15;
  const int j   = 64 * w + 4 * jg + qa;      // this lane's finalize target

  // prologue (all coalesced)
  uint4 wr[48];
#pragma unroll
  for (int i = 0; i < 48; i++) wr[i] = wp[(size_t)i * 512 + tid];
#pragma unroll
  for (int i = 0; i < 4; i++) wstat[i * 512 + tid] = wp[(size_t)(48 + i) * 512 + tid];
#pragma unroll
  for (int i = 0; i < 8; i++) wdyn[i * 512 + tid] = wp[(size_t)(52 + i) * 512 + tid];
  if (tid < 64) {
    uint4 z; z.x = z.y = z.z = z.w = 0u;
    h2[0][tid] = z;
  }
  __syncthreads();

  const uint4* wsrc = wp + (size_t)60 * 512 + tid;   // c 60..63 (kq 15, streamed)
  const float* pxj  = px + (size_t)b * TT * HIDD + j;
  float rmq = -INFINITY;

  // h-store address for this lane's j (ushort units), matches read layout:
  // h[k] lives at chunk p=((k>>3)&15)*4+(k>>7), slot k&7.
  const int kp = (j >> 3) & 15, qp = j >> 7, rp = j & 7;
  const int hidx = ((kp * 4 + qp) << 3) + rp;
  unsigned short* hw0 = (unsigned short*)&h2[0][0];
  unsigned short* hw1 = (unsigned short*)&h2[1][0];

  for (int t = 0; t < TT; t++) {
    const int cur = t & 1;

    // early issues: scalar px + the 4 streamed chunks (consumed LAST)
    float pxs = pxj[(size_t)t * HIDD];
    uint4 s0 = wsrc[0], s1 = wsrc[512], s2 = wsrc[1024], s3 = wsrc[1536];

    const uint4* hb = &h2[cur][0];
    float a0 = 0.f, a1 = 0.f, a2 = 0.f, a3 = 0.f;

    // kq 0..11: register weights
#pragma unroll
    for (int kq = 0; kq < 12; kq++)
      DOT4(hb[kq * 4 + qa], wr[4 * kq + 0], wr[4 * kq + 1], wr[4 * kq + 2], wr[4 * kq + 3]);
    // kq 12: static LDS
    DOT4(hb[12 * 4 + qa], wstat[tid], wstat[512 + tid],
         wstat[1024 + tid], wstat[1536 + tid]);
    // kq 13..14: dynamic LDS
    DOT4(hb[13 * 4 + qa], wdyn[tid], wdyn[512 + tid],
         wdyn[1024 + tid], wdyn[1536 + tid]);
    DOT4(hb[14 * 4 + qa], wdyn[2048 + tid], wdyn[2560 + tid],
         wdyn[3072 + tid], wdyn[3584 + tid]);
    // kq 15: streamed (latency fully hidden by the 15 DOT4s above)
    DOT4(hb[15 * 4 + qa], s0, s1, s2, s3);

    // 2-level butterfly over qa: all lanes end with complete sums
    a0 += __shfl_xor(a0, 16); a1 += __shfl_xor(a1, 16);
    a2 += __shfl_xor(a2, 16); a3 += __shfl_xor(a3, 16);
    a0 += __shfl_xor(a0, 32); a1 += __shfl_xor(a1, 32);
    a2 += __shfl_xor(a2, 32); a3 += __shfl_xor(a3, 32);

    // all-lane finalize: each lane handles its one j
    float t01 = (qa & 1) ? a1 : a0;
    float t23 = (qa & 1) ? a3 : a2;
    float aq  = (qa & 2) ? t23 : t01;
    float hv  = fast_tanh(aq + pxs);
    rmq = fmaxf(rmq, hv);
    _Float16 hf = (_Float16)hv;
    (cur ? hw0 : hw1)[hidx] = __builtin_bit_cast(unsigned short, hf);
    if (t == TT - 1)
      out[2 * BB + (size_t)b * HIDD + j] = hv;
    __syncthreads();
  }

  // pooled max -> logits (pl overlays dynamic weight LDS; weights dead now)
  float* pl = (float*)wdyn;
  pl[j] = rmq;                         // bijection: 512 threads -> 512 j
  __syncthreads();
  {
    float pv = pl[tid];
    float q0 = pv * W2[tid];
    float q1 = pv * W2[HIDD + tid];
#pragma unroll
    for (int off = 32; off; off >>= 1) {
      q0 += __shfl_down(q0, off);
      q1 += __shfl_down(q1, off);
    }
    if (l == 0) { red[0][w] = q0; red[1][w] = q1; }
  }
  __syncthreads();
  if (tid < 2) {
    float s = b2[tid];
#pragma unroll
    for (int i = 0; i < 8; i++) s += red[tid][i];
    out[b * 2 + tid] = s;
  }
}

// ---------------------------------------------------------------------------
extern "C" void kernel_launch(void* const* d_in, const int* in_sizes, int n_in,
                              void* d_out, int out_size, void* d_ws, size_t ws_size,
                              hipStream_t stream)
{
  const int*   x   = (const int*)d_in[0];
  const float* emb = (const float*)d_in[1];
  const float* W1  = (const float*)d_in[2];
  const float* b1  = (const float*)d_in[3];
  const float* W2  = (const float*)d_in[4];
  const float* b2  = (const float*)d_in[5];
  float* out = (float*)d_out;
  char* ws = (char*)d_ws;

  uint4* wp = (uint4*)ws;                        // 512 KB repacked fp16 W1h
  float* px = (float*)(ws + (1 << 19));          // 64 MB
  const size_t need = (size_t)(1 << 19) + (size_t)BB * TT * HIDD * sizeof(float);
  if (ws_size < need) return;

  repack_w1h<<<128, 256, 0, stream>>>(W1, wp);
  {
    dim3 g(TT * BB / 128, HIDD / 128);           // (256, 4)
    px_gemm<<<g, 256, 0, stream>>>(x, emb, W1, b1, px);
  }

  const size_t dynBytes = (size_t)8 * 512 * sizeof(uint4);   // 65536 B
  // r8 empirically launched 57 KB dynamic + 58 KB static with no attribute;
  // total here = 64 KB dyn + 34.3 KB static = 98.3 KB < 160 KB/CU.
  elman_v9<<<dim3(BB), dim3(512), dynBytes, stream>>>(wp, px, W2, b2, out);
}

// Round 10
// 972.447 us; speedup vs baseline: 1.3173x; 1.1688x over previous
//
#include <hip/hip_runtime.h>
#include <math.h>

#define TT   512
#define BB   64
#define EMBD 512
#define HIDD 512

typedef _Float16 half2v __attribute__((ext_vector_type(2)));

__device__ __forceinline__ float fdot2(unsigned a, unsigned b, float c) {
  half2v av = __builtin_bit_cast(half2v, a);
  half2v bv = __builtin_bit_cast(half2v, b);
#if __has_builtin(__builtin_amdgcn_fdot2)
  return __builtin_amdgcn_fdot2(av, bv, c, false);
#else
  return c + (float)av.x * (float)bv.x + (float)av.y * (float)bv.y;
#endif
}

__device__ __forceinline__ float fast_tanh(float x) {
  float e = __expf(2.0f * x);
  return 1.0f - 2.0f * __builtin_amdgcn_rcpf(e + 1.0f);
}

__device__ __forceinline__ unsigned pack2(float a, float b) {
  half2v hv; hv.x = (_Float16)a; hv.y = (_Float16)b;
  return __builtin_bit_cast(unsigned, hv);
}

// ---------------------------------------------------------------------------
// K0: repack fp32 W1h -> fp16 chunks (r6 layout, proven).
// elman thread tid: w=tid>>6, l=tid&63, qa=l>>4, jg=l&15.
// chunk c (0..63): jo=c&3, kq=c>>2. Covers j=64w+4jg+jo, k=128qa+8kq..+8,
// packed as 4 dwords of (even,odd) fp16 pairs. wp[c*512+tid].
// ---------------------------------------------------------------------------
__global__ __launch_bounds__(256) void repack_w1h(
    const float* __restrict__ W1, uint4* __restrict__ wp)
{
  const int gid = blockIdx.x * 256 + threadIdx.x;   // 0..32767
  const int c   = gid >> 9;
  const int tid = gid & 511;
  const int w = tid >> 6, l = tid & 63;
  const int qa = l >> 4, jg = l & 15;
  const int jo = c & 3, kq = c >> 2;
  const int j  = 64 * w + 4 * jg + jo;
  const int k0 = 128 * qa + 8 * kq;
  const float* src = W1 + (size_t)j * (2 * EMBD) + EMBD + k0;
  unsigned r[4];
#pragma unroll
  for (int q = 0; q < 4; q++) r[q] = pack2(src[2 * q], src[2 * q + 1]);
  uint4 u; u.x = r[0]; u.y = r[1]; u.z = r[2]; u.w = r[3];
  wp[gid] = u;
}

// ---------------------------------------------------------------------------
// K1: px[m][j] = b1[j] + sum_k emb[x[m]][k] * W1[j][k]  (fp32 tile GEMM)
// ---------------------------------------------------------------------------
__global__ __launch_bounds__(256) void px_gemm(
    const int* __restrict__ x, const float* __restrict__ emb,
    const float* __restrict__ W1, const float* __restrict__ b1,
    float* __restrict__ px)
{
  __shared__ float As[8][132];
  __shared__ float Bs[8][132];
  __shared__ int stok[128];
  const int tid = threadIdx.x;
  const int m0 = blockIdx.x * 128;
  const int j0 = blockIdx.y * 128;
  if (tid < 128) stok[tid] = x[m0 + tid];
  __syncthreads();
  const int lr = tid >> 1;
  const int lh = (tid & 1) * 4;
  const int ty = tid >> 4, tx = tid & 15;
  const size_t arow = (size_t)stok[lr] * EMBD;
  const float* brow = W1 + (size_t)(j0 + lr) * (2 * EMBD);

  float acc[8][8];
#pragma unroll
  for (int i = 0; i < 8; i++)
#pragma unroll
    for (int q = 0; q < 8; q++) acc[i][q] = 0.f;

  for (int k0 = 0; k0 < EMBD; k0 += 8) {
    float4 av = *(const float4*)(emb + arow + k0 + lh);
    float4 bv = *(const float4*)(brow + k0 + lh);
    __syncthreads();
    As[lh + 0][lr] = av.x; As[lh + 1][lr] = av.y; As[lh + 2][lr] = av.z; As[lh + 3][lr] = av.w;
    Bs[lh + 0][lr] = bv.x; Bs[lh + 1][lr] = bv.y; Bs[lh + 2][lr] = bv.z; Bs[lh + 3][lr] = bv.w;
    __syncthreads();
#pragma unroll
    for (int kk = 0; kk < 8; kk++) {
      float4 a0 = *(const float4*)&As[kk][ty * 8];
      float4 a1 = *(const float4*)&As[kk][ty * 8 + 4];
      float4 c0 = *(const float4*)&Bs[kk][tx * 8];
      float4 c1 = *(const float4*)&Bs[kk][tx * 8 + 4];
      float a[8] = {a0.x,a0.y,a0.z,a0.w,a1.x,a1.y,a1.z,a1.w};
      float bb[8] = {c0.x,c0.y,c0.z,c0.w,c1.x,c1.y,c1.z,c1.w};
#pragma unroll
      for (int i = 0; i < 8; i++)
#pragma unroll
        for (int q = 0; q < 8; q++)
          acc[i][q] = fmaf(a[i], bb[q], acc[i][q]);
    }
  }
  const float* bp = b1 + j0 + tx * 8;
  float bias0[8];
#pragma unroll
  for (int q = 0; q < 8; q++) bias0[q] = bp[q];
#pragma unroll
  for (int i = 0; i < 8; i++) {
    float o[8];
#pragma unroll
    for (int q = 0; q < 8; q++) o[q] = acc[i][q] + bias0[q];
    float* dst = px + (size_t)(m0 + ty * 8 + i) * HIDD + j0 + tx * 8;
    *(float4*)dst       = make_float4(o[0], o[1], o[2], o[3]);
    *(float4*)(dst + 4) = make_float4(o[4], o[5], o[6], o[7]);
  }
}

// ---------------------------------------------------------------------------
// K2: recurrence v10 = r6 structure with ALL-STATIC LDS.
// Rationale: the compiler budgets VGPRs from STATIC LDS only; previous
// rounds' small static + big dynamic made it target 4 waves/SIMD -> 128
// arch VGPRs -> weight array overflowed to AGPRs -> ~192 v_accvgpr_read
// per thread per step. Declaring 120KB static forces the 1-block/CU truth
// at compile time -> 2 waves/SIMD -> 256-reg budget -> weights in arch
// VGPRs, no copies.
// 64 wgs x 512 thr. Lane l: qa=l>>4, jg=l&15; thread: 4 j x 128 k.
// Weights: c 0..48 in 49 reg chunks, c 49..63 in 120KB static LDS.
// Zero per-step global streaming. h chunks at p=kq*4+qa (conflict-free).
// One barrier/step; 2-level shfl_xor merge; l<16 finalize (r6-proven).
// ---------------------------------------------------------------------------
#define DOT4(HH, W0, W1v, W2v, W3v) do {                                    \
    const uint4 hh = (HH);                                                  \
    a0=fdot2((W0).x,hh.x,a0);  a0=fdot2((W0).y,hh.y,a0);                    \
    a0=fdot2((W0).z,hh.z,a0);  a0=fdot2((W0).w,hh.w,a0);                    \
    a1=fdot2((W1v).x,hh.x,a1); a1=fdot2((W1v).y,hh.y,a1);                   \
    a1=fdot2((W1v).z,hh.z,a1); a1=fdot2((W1v).w,hh.w,a1);                   \
    a2=fdot2((W2v).x,hh.x,a2); a2=fdot2((W2v).y,hh.y,a2);                   \
    a2=fdot2((W2v).z,hh.z,a2); a2=fdot2((W2v).w,hh.w,a2);                   \
    a3=fdot2((W3v).x,hh.x,a3); a3=fdot2((W3v).y,hh.y,a3);                   \
    a3=fdot2((W3v).z,hh.z,a3); a3=fdot2((W3v).w,hh.w,a3);                   \
  } while (0)

__attribute__((amdgpu_flat_work_group_size(512, 512), amdgpu_waves_per_eu(2)))
__global__ void elman_v10(
    const uint4* __restrict__ wp, const float* __restrict__ px,
    const float* __restrict__ W2, const float* __restrict__ b2,
    float* __restrict__ out)
{
  __shared__ uint4 wlds[15 * 512];     // 120 KB static (c 49..63)
  __shared__ uint4 h2[2][64];          // packed fp16 h, dbuf, p = kq*4+qa
  __shared__ float red[2][8];

  const int b   = blockIdx.x;
  const int tid = threadIdx.x;
  const int w   = tid >> 6, l = tid & 63;
  const int qa  = l >> 4, jg = l & 15;

  // prologue: 49 reg chunks + 15 LDS chunks (all coalesced)
  uint4 wr[49];
#pragma unroll
  for (int i = 0; i < 49; i++) wr[i] = wp[(size_t)i * 512 + tid];
#pragma unroll
  for (int i = 0; i < 15; i++) wlds[i * 512 + tid] = wp[(size_t)(49 + i) * 512 + tid];
  if (tid < 64) {
    uint4 z; z.x = z.y = z.z = z.w = 0u;
    h2[0][tid] = z;
  }
  __syncthreads();

  const float* pxb = px + (size_t)b * TT * HIDD;
  float rm0 = -INFINITY, rm1 = -INFINITY, rm2 = -INFINITY, rm3 = -INFINITY;

  for (int t = 0; t < TT; t++) {
    const int cur = t & 1;

    // early issue: px for finalize lanes (latency hidden under the dot)
    float4 pxv = make_float4(0.f, 0.f, 0.f, 0.f);
    if (l < 16)
      pxv = *(const float4*)(pxb + (size_t)t * HIDD + 64 * w + 4 * jg);

    const uint4* hb = &h2[cur][0];
    float a0 = 0.f, a1 = 0.f, a2 = 0.f, a3 = 0.f;

    // kq 0..11: register weights (c = 4*kq + jo)
#pragma unroll
    for (int kq = 0; kq < 12; kq++)
      DOT4(hb[kq * 4 + qa], wr[4 * kq + 0], wr[4 * kq + 1], wr[4 * kq + 2], wr[4 * kq + 3]);
    // kq 12: c48 in reg, c49..51 in LDS
    DOT4(hb[12 * 4 + qa], wr[48],
         wlds[0 * 512 + tid], wlds[1 * 512 + tid], wlds[2 * 512 + tid]);
    // kq 13..15: LDS chunks c52..63 -> wlds[3..14]
    DOT4(hb[13 * 4 + qa], wlds[3 * 512 + tid], wlds[4 * 512 + tid],
         wlds[5 * 512 + tid], wlds[6 * 512 + tid]);
    DOT4(hb[14 * 4 + qa], wlds[7 * 512 + tid], wlds[8 * 512 + tid],
         wlds[9 * 512 + tid], wlds[10 * 512 + tid]);
    DOT4(hb[15 * 4 + qa], wlds[11 * 512 + tid], wlds[12 * 512 + tid],
         wlds[13 * 512 + tid], wlds[14 * 512 + tid]);

    // merge across 4 k-quarters
    a0 += __shfl_xor(a0, 16); a1 += __shfl_xor(a1, 16);
    a2 += __shfl_xor(a2, 16); a3 += __shfl_xor(a3, 16);
    a0 += __shfl_xor(a0, 32); a1 += __shfl_xor(a1, 32);
    a2 += __shfl_xor(a2, 32); a3 += __shfl_xor(a3, 32);

    if (l < 16) {
      float h0 = fast_tanh(a0 + pxv.x);
      float h1 = fast_tanh(a1 + pxv.y);
      float h2n = fast_tanh(a2 + pxv.z);
      float h3 = fast_tanh(a3 + pxv.w);
      rm0 = fmaxf(rm0, h0); rm1 = fmaxf(rm1, h1);
      rm2 = fmaxf(rm2, h2n); rm3 = fmaxf(rm3, h3);
      // write h[j0..j0+3], j0 = 64w+4jg, into p = kqw*4+qw layout
      const int qw  = w >> 1;
      const int kqw = (w & 1) * 8 + (jg >> 1);
      const int di  = (kqw * 4 + qw) * 4 + (jg & 1) * 2;   // dword index
      unsigned* hw = (unsigned*)&h2[cur ^ 1][0];
      *(uint2*)&hw[di] = make_uint2(pack2(h0, h1), pack2(h2n, h3));
      if (t == TT - 1)
        *(float4*)(out + 2 * BB + (size_t)b * HIDD + 64 * w + 4 * jg) =
            make_float4(h0, h1, h2n, h3);
    }
    __syncthreads();
  }

  // pooled max -> logits (pl overlays weight LDS; weights dead now)
  float* pl = (float*)wlds;
  if (l < 16)
    *(float4*)&pl[64 * w + 4 * jg] = make_float4(rm0, rm1, rm2, rm3);
  __syncthreads();
  {
    float pv = pl[tid];
    float q0 = pv * W2[tid];
    float q1 = pv * W2[HIDD + tid];
#pragma unroll
    for (int off = 32; off; off >>= 1) {
      q0 += __shfl_down(q0, off);
      q1 += __shfl_down(q1, off);
    }
    if (l == 0) { red[0][w] = q0; red[1][w] = q1; }
  }
  __syncthreads();
  if (tid < 2) {
    float s = b2[tid];
#pragma unroll
    for (int i = 0; i < 8; i++) s += red[tid][i];
    out[b * 2 + tid] = s;
  }
}

// ---------------------------------------------------------------------------
extern "C" void kernel_launch(void* const* d_in, const int* in_sizes, int n_in,
                              void* d_out, int out_size, void* d_ws, size_t ws_size,
                              hipStream_t stream)
{
  const int*   x   = (const int*)d_in[0];
  const float* emb = (const float*)d_in[1];
  const float* W1  = (const float*)d_in[2];
  const float* b1  = (const float*)d_in[3];
  const float* W2  = (const float*)d_in[4];
  const float* b2  = (const float*)d_in[5];
  float* out = (float*)d_out;
  char* ws = (char*)d_ws;

  uint4* wp = (uint4*)ws;                        // 512 KB repacked fp16 W1h
  float* px = (float*)(ws + (1 << 19));          // 64 MB
  const size_t need = (size_t)(1 << 19) + (size_t)BB * TT * HIDD * sizeof(float);
  if (ws_size < need) return;

  repack_w1h<<<128, 256, 0, stream>>>(W1, wp);
  {
    dim3 g(TT * BB / 128, HIDD / 128);           // (256, 4)
    px_gemm<<<g, 256, 0, stream>>>(x, emb, W1, b1, px);
  }

  elman_v10<<<dim3(BB), dim3(512), 0, stream>>>(wp, px, W2, b2, out);
}

// Round 11
// 971.854 us; speedup vs baseline: 1.3181x; 1.0006x over previous
//
#include <hip/hip_runtime.h>
#include <math.h>

#define TT   512
#define BB   64
#define EMBD 512
#define HIDD 512

typedef _Float16 half2v __attribute__((ext_vector_type(2)));
typedef _Float16 half8  __attribute__((ext_vector_type(8)));
typedef float    f32x4  __attribute__((ext_vector_type(4)));

__device__ __forceinline__ float fdot2(unsigned a, unsigned b, float c) {
  half2v av = __builtin_bit_cast(half2v, a);
  half2v bv = __builtin_bit_cast(half2v, b);
#if __has_builtin(__builtin_amdgcn_fdot2)
  return __builtin_amdgcn_fdot2(av, bv, c, false);
#else
  return c + (float)av.x * (float)bv.x + (float)av.y * (float)bv.y;
#endif
}

__device__ __forceinline__ float fast_tanh(float x) {
  float e = __expf(2.0f * x);
  return 1.0f - 2.0f * __builtin_amdgcn_rcpf(e + 1.0f);
}

__device__ __forceinline__ unsigned pack2(float a, float b) {
  half2v hv; hv.x = (_Float16)a; hv.y = (_Float16)b;
  return __builtin_bit_cast(unsigned, hv);
}

__device__ __forceinline__ uint4 pack8(float4 f0, float4 f1) {
  uint4 u;
  u.x = pack2(f0.x, f0.y); u.y = pack2(f0.z, f0.w);
  u.z = pack2(f1.x, f1.y); u.w = pack2(f1.z, f1.w);
  return u;
}

// ---------------------------------------------------------------------------
// K0: repack fp32 W1h -> fp16 chunks (r6/r10 layout, proven).
// ---------------------------------------------------------------------------
__global__ __launch_bounds__(256) void repack_w1h(
    const float* __restrict__ W1, uint4* __restrict__ wp)
{
  const int gid = blockIdx.x * 256 + threadIdx.x;   // 0..32767
  const int c   = gid >> 9;
  const int tid = gid & 511;
  const int w = tid >> 6, l = tid & 63;
  const int qa = l >> 4, jg = l & 15;
  const int jo = c & 3, kq = c >> 2;
  const int j  = 64 * w + 4 * jg + jo;
  const int k0 = 128 * qa + 8 * kq;
  const float* src = W1 + (size_t)j * (2 * EMBD) + EMBD + k0;
  unsigned r[4];
#pragma unroll
  for (int q = 0; q < 4; q++) r[q] = pack2(src[2 * q], src[2 * q + 1]);
  uint4 u; u.x = r[0]; u.y = r[1]; u.z = r[2]; u.w = r[3];
  wp[gid] = u;
}

// ---------------------------------------------------------------------------
// K1 (primary): px via fp16 MFMA.  px[m][j] = b1[j] + sum_k A[m][k]*W1[j][k]
// A row m = emb[x[m]], fp32 -> fp16 staged in LDS. Block = 128 M x 256 N,
// 256 thr (4 waves); wave wv computes 128 x 64 via 8x4 frags of 16x16x32.
// K staged in 4 chunks of 128. XOR-swizzled LDS (slot ^= row&15).
// Frag layout (m89/m91/m92-verified): A/B lane l: row l&15, k (l>>4)*8..+8;
// C/D: col l&15, row (l>>4)*4+reg.
// ---------------------------------------------------------------------------
#if __has_builtin(__builtin_amdgcn_mfma_f32_16x16x32_f16)
#define PX_MFMA 1

__global__ __launch_bounds__(256, 1) void px_mfma(
    const int* __restrict__ xx, const float* __restrict__ emb,
    const float* __restrict__ W1, const float* __restrict__ b1,
    float* __restrict__ px)
{
  __shared__ uint4 At[128 * 16];     // 32 KB: 128 rows x 256B (16 slots)
  __shared__ uint4 Bt[256 * 16];     // 64 KB: 256 rows x 256B
  __shared__ int stok[128];

  const int tid = threadIdx.x;
  const int wv  = tid >> 6, l = tid & 63;
  const int m0  = blockIdx.x * 128;
  const int j0  = blockIdx.y * 256;

  if (tid < 128) stok[tid] = xx[m0 + tid];

  // acc init with bias (bias depends only on col)
  f32x4 acc[8][4];
#pragma unroll
  for (int q = 0; q < 4; q++) {
    const float bc = b1[j0 + wv * 64 + 16 * q + (l & 15)];
#pragma unroll
    for (int i = 0; i < 8; i++) { acc[i][q].x = bc; acc[i][q].y = bc; acc[i][q].z = bc; acc[i][q].w = bc; }
  }

  for (int kc = 0; kc < 4; kc++) {
    __syncthreads();                 // stok ready / previous compute done
    {
      // stage A: thread (r = tid>>1, h = tid&1) covers 64 floats
      const int r = tid >> 1, h = tid & 1;
      const float4* s4 = (const float4*)(emb + (size_t)stok[r] * EMBD + kc * 128 + h * 64);
#pragma unroll
      for (int i = 0; i < 8; i++)
        At[r * 16 + ((8 * h + i) ^ (r & 15))] = pack8(s4[2 * i], s4[2 * i + 1]);
      // stage B: thread r = tid covers full row j0+r, 128 floats
      const float4* t4 = (const float4*)(W1 + (size_t)(j0 + tid) * (2 * EMBD) + kc * 128);
#pragma unroll
      for (int i = 0; i < 16; i++)
        Bt[tid * 16 + (i ^ (tid & 15))] = pack8(t4[2 * i], t4[2 * i + 1]);
    }
    __syncthreads();

#pragma unroll
    for (int ks = 0; ks < 4; ks++) {
      const int so = ks * 4 + (l >> 4);     // k-slot within row
      half8 a[8], bfr[4];
#pragma unroll
      for (int i = 0; i < 8; i++) {
        const int ra = 16 * i + (l & 15);
        a[i] = __builtin_bit_cast(half8, At[ra * 16 + (so ^ (ra & 15))]);
      }
#pragma unroll
      for (int q = 0; q < 4; q++) {
        const int rb = wv * 64 + 16 * q + (l & 15);
        bfr[q] = __builtin_bit_cast(half8, Bt[rb * 16 + (so ^ (rb & 15))]);
      }
#pragma unroll
      for (int i = 0; i < 8; i++)
#pragma unroll
        for (int q = 0; q < 4; q++)
          acc[i][q] = __builtin_amdgcn_mfma_f32_16x16x32_f16(a[i], bfr[q], acc[i][q], 0, 0, 0);
    }
  }

  // epilogue: D lane l reg p -> row (l>>4)*4+p, col l&15
#pragma unroll
  for (int i = 0; i < 8; i++) {
    const int mrow = m0 + 16 * i + (l >> 4) * 4;
#pragma unroll
    for (int q = 0; q < 4; q++) {
      const int col = j0 + wv * 64 + 16 * q + (l & 15);
      float* dst = px + (size_t)mrow * HIDD + col;
      dst[0 * HIDD] = acc[i][q].x;
      dst[1 * HIDD] = acc[i][q].y;
      dst[2 * HIDD] = acc[i][q].z;
      dst[3 * HIDD] = acc[i][q].w;
    }
  }
}
#else
#define PX_MFMA 0
#endif

// ---------------------------------------------------------------------------
// K1 (fallback): fp32 tile GEMM (proven).
// ---------------------------------------------------------------------------
__global__ __launch_bounds__(256) void px_gemm(
    const int* __restrict__ x, const float* __restrict__ emb,
    const float* __restrict__ W1, const float* __restrict__ b1,
    float* __restrict__ px)
{
  __shared__ float As[8][132];
  __shared__ float Bs[8][132];
  __shared__ int stok[128];
  const int tid = threadIdx.x;
  const int m0 = blockIdx.x * 128;
  const int j0 = blockIdx.y * 128;
  if (tid < 128) stok[tid] = x[m0 + tid];
  __syncthreads();
  const int lr = tid >> 1;
  const int lh = (tid & 1) * 4;
  const int ty = tid >> 4, tx = tid & 15;
  const size_t arow = (size_t)stok[lr] * EMBD;
  const float* brow = W1 + (size_t)(j0 + lr) * (2 * EMBD);

  float acc[8][8];
#pragma unroll
  for (int i = 0; i < 8; i++)
#pragma unroll
    for (int q = 0; q < 8; q++) acc[i][q] = 0.f;

  for (int k0 = 0; k0 < EMBD; k0 += 8) {
    float4 av = *(const float4*)(emb + arow + k0 + lh);
    float4 bv = *(const float4*)(brow + k0 + lh);
    __syncthreads();
    As[lh + 0][lr] = av.x; As[lh + 1][lr] = av.y; As[lh + 2][lr] = av.z; As[lh + 3][lr] = av.w;
    Bs[lh + 0][lr] = bv.x; Bs[lh + 1][lr] = bv.y; Bs[lh + 2][lr] = bv.z; Bs[lh + 3][lr] = bv.w;
    __syncthreads();
#pragma unroll
    for (int kk = 0; kk < 8; kk++) {
      float4 a0 = *(const float4*)&As[kk][ty * 8];
      float4 a1 = *(const float4*)&As[kk][ty * 8 + 4];
      float4 c0 = *(const float4*)&Bs[kk][tx * 8];
      float4 c1 = *(const float4*)&Bs[kk][tx * 8 + 4];
      float a[8] = {a0.x,a0.y,a0.z,a0.w,a1.x,a1.y,a1.z,a1.w};
      float bb[8] = {c0.x,c0.y,c0.z,c0.w,c1.x,c1.y,c1.z,c1.w};
#pragma unroll
      for (int i = 0; i < 8; i++)
#pragma unroll
        for (int q = 0; q < 8; q++)
          acc[i][q] = fmaf(a[i], bb[q], acc[i][q]);
    }
  }
  const float* bp = b1 + j0 + tx * 8;
  float bias0[8];
#pragma unroll
  for (int q = 0; q < 8; q++) bias0[q] = bp[q];
#pragma unroll
  for (int i = 0; i < 8; i++) {
    float o[8];
#pragma unroll
    for (int q = 0; q < 8; q++) o[q] = acc[i][q] + bias0[q];
    float* dst = px + (size_t)(m0 + ty * 8 + i) * HIDD + j0 + tx * 8;
    *(float4*)dst       = make_float4(o[0], o[1], o[2], o[3]);
    *(float4*)(dst + 4) = make_float4(o[4], o[5], o[6], o[7]);
  }
}

// ---------------------------------------------------------------------------
// K2: recurrence v10 (byte-identical to round 10, best proven: ~790 us).
// ---------------------------------------------------------------------------
#define DOT4(HH, W0, W1v, W2v, W3v) do {                                    \
    const uint4 hh = (HH);                                                  \
    a0=fdot2((W0).x,hh.x,a0);  a0=fdot2((W0).y,hh.y,a0);                    \
    a0=fdot2((W0).z,hh.z,a0);  a0=fdot2((W0).w,hh.w,a0);                    \
    a1=fdot2((W1v).x,hh.x,a1); a1=fdot2((W1v).y,hh.y,a1);                   \
    a1=fdot2((W1v).z,hh.z,a1); a1=fdot2((W1v).w,hh.w,a1);                   \
    a2=fdot2((W2v).x,hh.x,a2); a2=fdot2((W2v).y,hh.y,a2);                   \
    a2=fdot2((W2v).z,hh.z,a2); a2=fdot2((W2v).w,hh.w,a2);                   \
    a3=fdot2((W3v).x,hh.x,a3); a3=fdot2((W3v).y,hh.y,a3);                   \
    a3=fdot2((W3v).z,hh.z,a3); a3=fdot2((W3v).w,hh.w,a3);                   \
  } while (0)

__attribute__((amdgpu_flat_work_group_size(512, 512), amdgpu_waves_per_eu(2)))
__global__ void elman_v10(
    const uint4* __restrict__ wp, const float* __restrict__ px,
    const float* __restrict__ W2, const float* __restrict__ b2,
    float* __restrict__ out)
{
  __shared__ uint4 wlds[15 * 512];     // 120 KB static (c 49..63)
  __shared__ uint4 h2[2][64];          // packed fp16 h, dbuf, p = kq*4+qa
  __shared__ float red[2][8];

  const int b   = blockIdx.x;
  const int tid = threadIdx.x;
  const int w   = tid >> 6, l = tid & 63;
  const int qa  = l >> 4, jg = l & 15;

  uint4 wr[49];
#pragma unroll
  for (int i = 0; i < 49; i++) wr[i] = wp[(size_t)i * 512 + tid];
#pragma unroll
  for (int i = 0; i < 15; i++) wlds[i * 512 + tid] = wp[(size_t)(49 + i) * 512 + tid];
  if (tid < 64) {
    uint4 z; z.x = z.y = z.z = z.w = 0u;
    h2[0][tid] = z;
  }
  __syncthreads();

  const float* pxb = px + (size_t)b * TT * HIDD;
  float rm0 = -INFINITY, rm1 = -INFINITY, rm2 = -INFINITY, rm3 = -INFINITY;

  for (int t = 0; t < TT; t++) {
    const int cur = t & 1;

    float4 pxv = make_float4(0.f, 0.f, 0.f, 0.f);
    if (l < 16)
      pxv = *(const float4*)(pxb + (size_t)t * HIDD + 64 * w + 4 * jg);

    const uint4* hb = &h2[cur][0];
    float a0 = 0.f, a1 = 0.f, a2 = 0.f, a3 = 0.f;

#pragma unroll
    for (int kq = 0; kq < 12; kq++)
      DOT4(hb[kq * 4 + qa], wr[4 * kq + 0], wr[4 * kq + 1], wr[4 * kq + 2], wr[4 * kq + 3]);
    DOT4(hb[12 * 4 + qa], wr[48],
         wlds[0 * 512 + tid], wlds[1 * 512 + tid], wlds[2 * 512 + tid]);
    DOT4(hb[13 * 4 + qa], wlds[3 * 512 + tid], wlds[4 * 512 + tid],
         wlds[5 * 512 + tid], wlds[6 * 512 + tid]);
    DOT4(hb[14 * 4 + qa], wlds[7 * 512 + tid], wlds[8 * 512 + tid],
         wlds[9 * 512 + tid], wlds[10 * 512 + tid]);
    DOT4(hb[15 * 4 + qa], wlds[11 * 512 + tid], wlds[12 * 512 + tid],
         wlds[13 * 512 + tid], wlds[14 * 512 + tid]);

    a0 += __shfl_xor(a0, 16); a1 += __shfl_xor(a1, 16);
    a2 += __shfl_xor(a2, 16); a3 += __shfl_xor(a3, 16);
    a0 += __shfl_xor(a0, 32); a1 += __shfl_xor(a1, 32);
    a2 += __shfl_xor(a2, 32); a3 += __shfl_xor(a3, 32);

    if (l < 16) {
      float h0 = fast_tanh(a0 + pxv.x);
      float h1 = fast_tanh(a1 + pxv.y);
      float h2n = fast_tanh(a2 + pxv.z);
      float h3 = fast_tanh(a3 + pxv.w);
      rm0 = fmaxf(rm0, h0); rm1 = fmaxf(rm1, h1);
      rm2 = fmaxf(rm2, h2n); rm3 = fmaxf(rm3, h3);
      const int qw  = w >> 1;
      const int kqw = (w & 1) * 8 + (jg >> 1);
      const int di  = (kqw * 4 + qw) * 4 + (jg & 1) * 2;
      unsigned* hw = (unsigned*)&h2[cur ^ 1][0];
      *(uint2*)&hw[di] = make_uint2(pack2(h0, h1), pack2(h2n, h3));
      if (t == TT - 1)
        *(float4*)(out + 2 * BB + (size_t)b * HIDD + 64 * w + 4 * jg) =
            make_float4(h0, h1, h2n, h3);
    }
    __syncthreads();
  }

  float* pl = (float*)wlds;
  if (l < 16)
    *(float4*)&pl[64 * w + 4 * jg] = make_float4(rm0, rm1, rm2, rm3);
  __syncthreads();
  {
    float pv = pl[tid];
    float q0 = pv * W2[tid];
    float q1 = pv * W2[HIDD + tid];
#pragma unroll
    for (int off = 32; off; off >>= 1) {
      q0 += __shfl_down(q0, off);
      q1 += __shfl_down(q1, off);
    }
    if (l == 0) { red[0][w] = q0; red[1][w] = q1; }
  }
  __syncthreads();
  if (tid < 2) {
    float s = b2[tid];
#pragma unroll
    for (int i = 0; i < 8; i++) s += red[tid][i];
    out[b * 2 + tid] = s;
  }
}

// ---------------------------------------------------------------------------
extern "C" void kernel_launch(void* const* d_in, const int* in_sizes, int n_in,
                              void* d_out, int out_size, void* d_ws, size_t ws_size,
                              hipStream_t stream)
{
  const int*   x   = (const int*)d_in[0];
  const float* emb = (const float*)d_in[1];
  const float* W1  = (const float*)d_in[2];
  const float* b1  = (const float*)d_in[3];
  const float* W2  = (const float*)d_in[4];
  const float* b2  = (const float*)d_in[5];
  float* out = (float*)d_out;
  char* ws = (char*)d_ws;

  uint4* wp = (uint4*)ws;                        // 512 KB repacked fp16 W1h
  float* px = (float*)(ws + (1 << 19));          // 64 MB
  const size_t need = (size_t)(1 << 19) + (size_t)BB * TT * HIDD * sizeof(float);
  if (ws_size < need) return;

  repack_w1h<<<128, 256, 0, stream>>>(W1, wp);

#if PX_MFMA
  px_mfma<<<dim3(TT * BB / 128, HIDD / 256), 256, 0, stream>>>(x, emb, W1, b1, px);
#else
  {
    dim3 g(TT * BB / 128, HIDD / 128);           // (256, 4)
    px_gemm<<<g, 256, 0, stream>>>(x, emb, W1, b1, px);
  }
#endif

  elman_v10<<<dim3(BB), dim3(512), 0, stream>>>(wp, px, W2, b2, out);
}

// Round 12
// 855.304 us; speedup vs baseline: 1.4978x; 1.1363x over previous
//
#include <hip/hip_runtime.h>
#include <math.h>

#define TT   512
#define BB   64
#define EMBD 512
#define HIDD 512

typedef _Float16 half2v __attribute__((ext_vector_type(2)));
typedef _Float16 half8  __attribute__((ext_vector_type(8)));
typedef float    f32x4  __attribute__((ext_vector_type(4)));

__device__ __forceinline__ float fdot2(unsigned a, unsigned b, float c) {
  half2v av = __builtin_bit_cast(half2v, a);
  half2v bv = __builtin_bit_cast(half2v, b);
  return __builtin_amdgcn_fdot2(av, bv, c, false);
}

__device__ __forceinline__ float fast_tanh(float x) {
  float e = __expf(2.0f * x);
  return 1.0f - 2.0f * __builtin_amdgcn_rcpf(e + 1.0f);
}

__device__ __forceinline__ unsigned pack2(float a, float b) {
  half2v hv; hv.x = (_Float16)a; hv.y = (_Float16)b;
  return __builtin_bit_cast(unsigned, hv);
}

__device__ __forceinline__ uint4 pack8(float4 f0, float4 f1) {
  uint4 u;
  u.x = pack2(f0.x, f0.y); u.y = pack2(f0.z, f0.w);
  u.z = pack2(f1.x, f1.y); u.w = pack2(f1.z, f1.w);
  return u;
}

// ---------------------------------------------------------------------------
// K0: repack fp32 W1h -> fp16 chunks (r6/r10 layout, proven).
// ---------------------------------------------------------------------------
__global__ __launch_bounds__(256) void repack_w1h(
    const float* __restrict__ W1, uint4* __restrict__ wp)
{
  const int gid = blockIdx.x * 256 + threadIdx.x;   // 0..32767
  const int c   = gid >> 9;
  const int tid = gid & 511;
  const int w = tid >> 6, l = tid & 63;
  const int qa = l >> 4, jg = l & 15;
  const int jo = c & 3, kq = c >> 2;
  const int j  = 64 * w + 4 * jg + jo;
  const int k0 = 128 * qa + 8 * kq;
  const float* src = W1 + (size_t)j * (2 * EMBD) + EMBD + k0;
  unsigned r[4];
#pragma unroll
  for (int q = 0; q < 4; q++) r[q] = pack2(src[2 * q], src[2 * q + 1]);
  uint4 u; u.x = r[0]; u.y = r[1]; u.z = r[2]; u.w = r[3];
  wp[gid] = u;
}

// ---------------------------------------------------------------------------
// K1: px via fp16 MFMA (launched UNCONDITIONALLY — r11's __has_builtin gate
// evaluated false in the HOST pass and silently kept the fp32 fallback).
// px[m][j] = b1[j] + sum_k A[m][k]*W1[j][k]; A row m = emb[x[m]], fp32->fp16
// staged in LDS. Block = 128 M x 256 N, 256 thr (4 waves); wave wv computes
// 128 x 64 via 8x4 frags of 16x16x32. K staged in 4 chunks of 128.
// XOR-swizzled LDS (slot ^= row&15). Frag layout (m89/m91/m92-verified):
// A/B lane l: row l&15, k (l>>4)*8..+8; C/D: col l&15, row (l>>4)*4+reg.
// ---------------------------------------------------------------------------
__global__ __launch_bounds__(256, 1) void px_mfma(
    const int* __restrict__ xx, const float* __restrict__ emb,
    const float* __restrict__ W1, const float* __restrict__ b1,
    float* __restrict__ px)
{
  __shared__ uint4 At[128 * 16];     // 32 KB: 128 rows x 256B (16 slots)
  __shared__ uint4 Bt[256 * 16];     // 64 KB: 256 rows x 256B
  __shared__ int stok[128];

  const int tid = threadIdx.x;
  const int wv  = tid >> 6, l = tid & 63;
  const int m0  = blockIdx.x * 128;
  const int j0  = blockIdx.y * 256;

  if (tid < 128) stok[tid] = xx[m0 + tid];

  // acc init with bias (bias depends only on col)
  f32x4 acc[8][4];
#pragma unroll
  for (int q = 0; q < 4; q++) {
    const float bc = b1[j0 + wv * 64 + 16 * q + (l & 15)];
#pragma unroll
    for (int i = 0; i < 8; i++) { acc[i][q].x = bc; acc[i][q].y = bc; acc[i][q].z = bc; acc[i][q].w = bc; }
  }

  for (int kc = 0; kc < 4; kc++) {
    __syncthreads();                 // stok ready / previous compute done
    {
      // stage A: thread (r = tid>>1, h = tid&1) covers 64 floats
      const int r = tid >> 1, h = tid & 1;
      const float4* s4 = (const float4*)(emb + (size_t)stok[r] * EMBD + kc * 128 + h * 64);
#pragma unroll
      for (int i = 0; i < 8; i++)
        At[r * 16 + ((8 * h + i) ^ (r & 15))] = pack8(s4[2 * i], s4[2 * i + 1]);
      // stage B: thread r = tid covers full row j0+r, 128 floats
      const float4* t4 = (const float4*)(W1 + (size_t)(j0 + tid) * (2 * EMBD) + kc * 128);
#pragma unroll
      for (int i = 0; i < 16; i++)
        Bt[tid * 16 + (i ^ (tid & 15))] = pack8(t4[2 * i], t4[2 * i + 1]);
    }
    __syncthreads();

#pragma unroll
    for (int ks = 0; ks < 4; ks++) {
      const int so = ks * 4 + (l >> 4);     // k-slot within row
      half8 a[8], bfr[4];
#pragma unroll
      for (int i = 0; i < 8; i++) {
        const int ra = 16 * i + (l & 15);
        a[i] = __builtin_bit_cast(half8, At[ra * 16 + (so ^ (ra & 15))]);
      }
#pragma unroll
      for (int q = 0; q < 4; q++) {
        const int rb = wv * 64 + 16 * q + (l & 15);
        bfr[q] = __builtin_bit_cast(half8, Bt[rb * 16 + (so ^ (rb & 15))]);
      }
#pragma unroll
      for (int i = 0; i < 8; i++)
#pragma unroll
        for (int q = 0; q < 4; q++)
          acc[i][q] = __builtin_amdgcn_mfma_f32_16x16x32_f16(a[i], bfr[q], acc[i][q], 0, 0, 0);
    }
  }

  // epilogue: D lane l reg p -> row (l>>4)*4+p, col l&15
#pragma unroll
  for (int i = 0; i < 8; i++) {
    const int mrow = m0 + 16 * i + (l >> 4) * 4;
#pragma unroll
    for (int q = 0; q < 4; q++) {
      const int col = j0 + wv * 64 + 16 * q + (l & 15);
      float* dst = px + (size_t)mrow * HIDD + col;
      dst[0 * HIDD] = acc[i][q].x;
      dst[1 * HIDD] = acc[i][q].y;
      dst[2 * HIDD] = acc[i][q].z;
      dst[3 * HIDD] = acc[i][q].w;
    }
  }
}

// ---------------------------------------------------------------------------
// K2: recurrence v10 (byte-identical to round 10, best proven: ~790 us).
// ---------------------------------------------------------------------------
#define DOT4(HH, W0, W1v, W2v, W3v) do {                                    \
    const uint4 hh = (HH);                                                  \
    a0=fdot2((W0).x,hh.x,a0);  a0=fdot2((W0).y,hh.y,a0);                    \
    a0=fdot2((W0).z,hh.z,a0);  a0=fdot2((W0).w,hh.w,a0);                    \
    a1=fdot2((W1v).x,hh.x,a1); a1=fdot2((W1v).y,hh.y,a1);                   \
    a1=fdot2((W1v).z,hh.z,a1); a1=fdot2((W1v).w,hh.w,a1);                   \
    a2=fdot2((W2v).x,hh.x,a2); a2=fdot2((W2v).y,hh.y,a2);                   \
    a2=fdot2((W2v).z,hh.z,a2); a2=fdot2((W2v).w,hh.w,a2);                   \
    a3=fdot2((W3v).x,hh.x,a3); a3=fdot2((W3v).y,hh.y,a3);                   \
    a3=fdot2((W3v).z,hh.z,a3); a3=fdot2((W3v).w,hh.w,a3);                   \
  } while (0)

__attribute__((amdgpu_flat_work_group_size(512, 512), amdgpu_waves_per_eu(2)))
__global__ void elman_v10(
    const uint4* __restrict__ wp, const float* __restrict__ px,
    const float* __restrict__ W2, const float* __restrict__ b2,
    float* __restrict__ out)
{
  __shared__ uint4 wlds[15 * 512];     // 120 KB static (c 49..63)
  __shared__ uint4 h2[2][64];          // packed fp16 h, dbuf, p = kq*4+qa
  __shared__ float red[2][8];

  const int b   = blockIdx.x;
  const int tid = threadIdx.x;
  const int w   = tid >> 6, l = tid & 63;
  const int qa  = l >> 4, jg = l & 15;

  uint4 wr[49];
#pragma unroll
  for (int i = 0; i < 49; i++) wr[i] = wp[(size_t)i * 512 + tid];
#pragma unroll
  for (int i = 0; i < 15; i++) wlds[i * 512 + tid] = wp[(size_t)(49 + i) * 512 + tid];
  if (tid < 64) {
    uint4 z; z.x = z.y = z.z = z.w = 0u;
    h2[0][tid] = z;
  }
  __syncthreads();

  const float* pxb = px + (size_t)b * TT * HIDD;
  float rm0 = -INFINITY, rm1 = -INFINITY, rm2 = -INFINITY, rm3 = -INFINITY;

  for (int t = 0; t < TT; t++) {
    const int cur = t & 1;

    float4 pxv = make_float4(0.f, 0.f, 0.f, 0.f);
    if (l < 16)
      pxv = *(const float4*)(pxb + (size_t)t * HIDD + 64 * w + 4 * jg);

    const uint4* hb = &h2[cur][0];
    float a0 = 0.f, a1 = 0.f, a2 = 0.f, a3 = 0.f;

#pragma unroll
    for (int kq = 0; kq < 12; kq++)
      DOT4(hb[kq * 4 + qa], wr[4 * kq + 0], wr[4 * kq + 1], wr[4 * kq + 2], wr[4 * kq + 3]);
    DOT4(hb[12 * 4 + qa], wr[48],
         wlds[0 * 512 + tid], wlds[1 * 512 + tid], wlds[2 * 512 + tid]);
    DOT4(hb[13 * 4 + qa], wlds[3 * 512 + tid], wlds[4 * 512 + tid],
         wlds[5 * 512 + tid], wlds[6 * 512 + tid]);
    DOT4(hb[14 * 4 + qa], wlds[7 * 512 + tid], wlds[8 * 512 + tid],
         wlds[9 * 512 + tid], wlds[10 * 512 + tid]);
    DOT4(hb[15 * 4 + qa], wlds[11 * 512 + tid], wlds[12 * 512 + tid],
         wlds[13 * 512 + tid], wlds[14 * 512 + tid]);

    a0 += __shfl_xor(a0, 16); a1 += __shfl_xor(a1, 16);
    a2 += __shfl_xor(a2, 16); a3 += __shfl_xor(a3, 16);
    a0 += __shfl_xor(a0, 32); a1 += __shfl_xor(a1, 32);
    a2 += __shfl_xor(a2, 32); a3 += __shfl_xor(a3, 32);

    if (l < 16) {
      float h0 = fast_tanh(a0 + pxv.x);
      float h1 = fast_tanh(a1 + pxv.y);
      float h2n = fast_tanh(a2 + pxv.z);
      float h3 = fast_tanh(a3 + pxv.w);
      rm0 = fmaxf(rm0, h0); rm1 = fmaxf(rm1, h1);
      rm2 = fmaxf(rm2, h2n); rm3 = fmaxf(rm3, h3);
      const int qw  = w >> 1;
      const int kqw = (w & 1) * 8 + (jg >> 1);
      const int di  = (kqw * 4 + qw) * 4 + (jg & 1) * 2;
      unsigned* hw = (unsigned*)&h2[cur ^ 1][0];
      *(uint2*)&hw[di] = make_uint2(pack2(h0, h1), pack2(h2n, h3));
      if (t == TT - 1)
        *(float4*)(out + 2 * BB + (size_t)b * HIDD + 64 * w + 4 * jg) =
            make_float4(h0, h1, h2n, h3);
    }
    __syncthreads();
  }

  float* pl = (float*)wlds;
  if (l < 16)
    *(float4*)&pl[64 * w + 4 * jg] = make_float4(rm0, rm1, rm2, rm3);
  __syncthreads();
  {
    float pv = pl[tid];
    float q0 = pv * W2[tid];
    float q1 = pv * W2[HIDD + tid];
#pragma unroll
    for (int off = 32; off; off >>= 1) {
      q0 += __shfl_down(q0, off);
      q1 += __shfl_down(q1, off);
    }
    if (l == 0) { red[0][w] = q0; red[1][w] = q1; }
  }
  __syncthreads();
  if (tid < 2) {
    float s = b2[tid];
#pragma unroll
    for (int i = 0; i < 8; i++) s += red[tid][i];
    out[b * 2 + tid] = s;
  }
}

// ---------------------------------------------------------------------------
extern "C" void kernel_launch(void* const* d_in, const int* in_sizes, int n_in,
                              void* d_out, int out_size, void* d_ws, size_t ws_size,
                              hipStream_t stream)
{
  const int*   x   = (const int*)d_in[0];
  const float* emb = (const float*)d_in[1];
  const float* W1  = (const float*)d_in[2];
  const float* b1  = (const float*)d_in[3];
  const float* W2  = (const float*)d_in[4];
  const float* b2  = (const float*)d_in[5];
  float* out = (float*)d_out;
  char* ws = (char*)d_ws;

  uint4* wp = (uint4*)ws;                        // 512 KB repacked fp16 W1h
  float* px = (float*)(ws + (1 << 19));          // 64 MB
  const size_t need = (size_t)(1 << 19) + (size_t)BB * TT * HIDD * sizeof(float);
  if (ws_size < need) return;

  repack_w1h<<<128, 256, 0, stream>>>(W1, wp);
  px_mfma<<<dim3(TT * BB / 128, HIDD / 256), 256, 0, stream>>>(x, emb, W1, b1, px);
  elman_v10<<<dim3(BB), dim3(512), 0, stream>>>(wp, px, W2, b2, out);
}

// Round 13
// 805.903 us; speedup vs baseline: 1.5896x; 1.0613x over previous
//
#include <hip/hip_runtime.h>
#include <math.h>

#define TT   512
#define BB   64
#define EMBD 512
#define HIDD 512

typedef _Float16 half2v __attribute__((ext_vector_type(2)));
typedef _Float16 half8  __attribute__((ext_vector_type(8)));
typedef float    f32x4  __attribute__((ext_vector_type(4)));

__device__ __forceinline__ float fdot2(unsigned a, unsigned b, float c) {
  half2v av = __builtin_bit_cast(half2v, a);
  half2v bv = __builtin_bit_cast(half2v, b);
  return __builtin_amdgcn_fdot2(av, bv, c, false);
}

__device__ __forceinline__ float fast_tanh(float x) {
  float e = __expf(2.0f * x);
  return 1.0f - 2.0f * __builtin_amdgcn_rcpf(e + 1.0f);
}

__device__ __forceinline__ unsigned pack2(float a, float b) {
  half2v hv; hv.x = (_Float16)a; hv.y = (_Float16)b;
  return __builtin_bit_cast(unsigned, hv);
}

__device__ __forceinline__ uint4 pack8(float4 f0, float4 f1) {
  uint4 u;
  u.x = pack2(f0.x, f0.y); u.y = pack2(f0.z, f0.w);
  u.z = pack2(f1.x, f1.y); u.w = pack2(f1.z, f1.w);
  return u;
}

// ---------------------------------------------------------------------------
// K0: repack fp32 W1h -> fp16 chunks for the v11 wave-split-k mapping.
// elman thread tid: w=tid>>6 (q=w&3, hh=w>>2), l=tid&63.
// chunk c (0..63): jo=c&3, kq=c>>2. Covers j=256*hh+4*l+jo,
// k=128*q+8*kq..+8, packed as 4 dwords of (even,odd) fp16 pairs.
// ---------------------------------------------------------------------------
__global__ __launch_bounds__(256) void repack_w1h(
    const float* __restrict__ W1, uint4* __restrict__ wp)
{
  const int gid = blockIdx.x * 256 + threadIdx.x;   // 0..32767
  const int c   = gid >> 9;
  const int tid = gid & 511;
  const int w = tid >> 6, l = tid & 63;
  const int q = w & 3, hh = w >> 2;
  const int jo = c & 3, kq = c >> 2;
  const int j  = 256 * hh + 4 * l + jo;
  const int k0 = 128 * q + 8 * kq;
  const float* src = W1 + (size_t)j * (2 * EMBD) + EMBD + k0;
  unsigned r[4];
#pragma unroll
  for (int p = 0; p < 4; p++) r[p] = pack2(src[2 * p], src[2 * p + 1]);
  uint4 u; u.x = r[0]; u.y = r[1]; u.z = r[2]; u.w = r[3];
  wp[gid] = u;
}

// ---------------------------------------------------------------------------
// K1: px via fp16 MFMA (proven r12: ~50 us, MFMA-active).
// ---------------------------------------------------------------------------
__global__ __launch_bounds__(256, 1) void px_mfma(
    const int* __restrict__ xx, const float* __restrict__ emb,
    const float* __restrict__ W1, const float* __restrict__ b1,
    float* __restrict__ px)
{
  __shared__ uint4 At[128 * 16];     // 32 KB: 128 rows x 256B (16 slots)
  __shared__ uint4 Bt[256 * 16];     // 64 KB: 256 rows x 256B
  __shared__ int stok[128];

  const int tid = threadIdx.x;
  const int wv  = tid >> 6, l = tid & 63;
  const int m0  = blockIdx.x * 128;
  const int j0  = blockIdx.y * 256;

  if (tid < 128) stok[tid] = xx[m0 + tid];

  f32x4 acc[8][4];
#pragma unroll
  for (int q = 0; q < 4; q++) {
    const float bc = b1[j0 + wv * 64 + 16 * q + (l & 15)];
#pragma unroll
    for (int i = 0; i < 8; i++) { acc[i][q].x = bc; acc[i][q].y = bc; acc[i][q].z = bc; acc[i][q].w = bc; }
  }

  for (int kc = 0; kc < 4; kc++) {
    __syncthreads();
    {
      const int r = tid >> 1, h = tid & 1;
      const float4* s4 = (const float4*)(emb + (size_t)stok[r] * EMBD + kc * 128 + h * 64);
#pragma unroll
      for (int i = 0; i < 8; i++)
        At[r * 16 + ((8 * h + i) ^ (r & 15))] = pack8(s4[2 * i], s4[2 * i + 1]);
      const float4* t4 = (const float4*)(W1 + (size_t)(j0 + tid) * (2 * EMBD) + kc * 128);
#pragma unroll
      for (int i = 0; i < 16; i++)
        Bt[tid * 16 + (i ^ (tid & 15))] = pack8(t4[2 * i], t4[2 * i + 1]);
    }
    __syncthreads();

#pragma unroll
    for (int ks = 0; ks < 4; ks++) {
      const int so = ks * 4 + (l >> 4);
      half8 a[8], bfr[4];
#pragma unroll
      for (int i = 0; i < 8; i++) {
        const int ra = 16 * i + (l & 15);
        a[i] = __builtin_bit_cast(half8, At[ra * 16 + (so ^ (ra & 15))]);
      }
#pragma unroll
      for (int q = 0; q < 4; q++) {
        const int rb = wv * 64 + 16 * q + (l & 15);
        bfr[q] = __builtin_bit_cast(half8, Bt[rb * 16 + (so ^ (rb & 15))]);
      }
#pragma unroll
      for (int i = 0; i < 8; i++)
#pragma unroll
        for (int q = 0; q < 4; q++)
          acc[i][q] = __builtin_amdgcn_mfma_f32_16x16x32_f16(a[i], bfr[q], acc[i][q], 0, 0, 0);
    }
  }

#pragma unroll
  for (int i = 0; i < 8; i++) {
    const int mrow = m0 + 16 * i + (l >> 4) * 4;
#pragma unroll
    for (int q = 0; q < 4; q++) {
      const int col = j0 + wv * 64 + 16 * q + (l & 15);
      float* dst = px + (size_t)mrow * HIDD + col;
      dst[0 * HIDD] = acc[i][q].x;
      dst[1 * HIDD] = acc[i][q].y;
      dst[2 * HIDD] = acc[i][q].z;
      dst[3 * HIDD] = acc[i][q].w;
    }
  }
}

// ---------------------------------------------------------------------------
// K2: recurrence v11 — wave-uniform k-split.
// 64 wgs x 512 thr. Wave w: k-quarter q=w&3, j-half hh=w>>2.
// Lane l: j = 256*hh + 4*l + {0..3}, k in [128q, 128q+128).
// All h-chunk reads are WAVE-UNIFORM (pure broadcast, conflict-free);
// no shfls — merge via parts[q][j] round trip (coalesced); h store is
// linear b16; px is a coalesced b32. Two barriers/step.
// Weights: c0..48 reg (49 chunks), c49..63 static LDS (120 KB) — r10's
// proven residency, zero per-step global streaming.
// ---------------------------------------------------------------------------
#define DOT4(HH, W0, W1v, W2v, W3v) do {                                    \
    const uint4 hh = (HH);                                                  \
    a0=fdot2((W0).x,hh.x,a0);  a0=fdot2((W0).y,hh.y,a0);                    \
    a0=fdot2((W0).z,hh.z,a0);  a0=fdot2((W0).w,hh.w,a0);                    \
    a1=fdot2((W1v).x,hh.x,a1); a1=fdot2((W1v).y,hh.y,a1);                   \
    a1=fdot2((W1v).z,hh.z,a1); a1=fdot2((W1v).w,hh.w,a1);                   \
    a2=fdot2((W2v).x,hh.x,a2); a2=fdot2((W2v).y,hh.y,a2);                   \
    a2=fdot2((W2v).z,hh.z,a2); a2=fdot2((W2v).w,hh.w,a2);                   \
    a3=fdot2((W3v).x,hh.x,a3); a3=fdot2((W3v).y,hh.y,a3);                   \
    a3=fdot2((W3v).z,hh.z,a3); a3=fdot2((W3v).w,hh.w,a3);                   \
  } while (0)

__attribute__((amdgpu_flat_work_group_size(512, 512), amdgpu_waves_per_eu(2)))
__global__ void elman_v11(
    const uint4* __restrict__ wp, const float* __restrict__ px,
    const float* __restrict__ W2, const float* __restrict__ b2,
    float* __restrict__ out)
{
  __shared__ uint4 wlds[15 * 512];          // 120 KB static (c 49..63)
  __shared__ __align__(16) unsigned short hbuf[HIDD];   // 1 KB fp16 h
  __shared__ float parts[4][HIDD];          // 8 KB quarter partials
  __shared__ float red[2][8];

  const int b   = blockIdx.x;
  const int tid = threadIdx.x;
  const int w   = tid >> 6, l = tid & 63;
  const int q   = w & 3;                    // this wave's k-quarter
  const int hh  = w >> 2;                   // this wave's j-half
  const int jb  = 256 * hh + 4 * l;         // first of this thread's 4 j

  // prologue: 49 reg chunks + 15 LDS chunks (all coalesced)
  uint4 wr[49];
#pragma unroll
  for (int i = 0; i < 49; i++) wr[i] = wp[(size_t)i * 512 + tid];
#pragma unroll
  for (int i = 0; i < 15; i++) wlds[i * 512 + tid] = wp[(size_t)(49 + i) * 512 + tid];
  if (tid < 64) ((uint4*)hbuf)[tid] = make_uint4(0u, 0u, 0u, 0u);
  __syncthreads();

  const uint4* hq = (const uint4*)hbuf + 16 * q;   // wave-uniform base
  const float* pxj = px + (size_t)b * TT * HIDD + tid;
  float rmq = -INFINITY;

  for (int t = 0; t < TT; t++) {
    // early issue: this thread's px (used post-barrier in finalize)
    float pxs = pxj[(size_t)t * HIDD];

    float a0 = 0.f, a1 = 0.f, a2 = 0.f, a3 = 0.f;

    // kq 0..11: register weights (h reads are wave-uniform broadcasts)
#pragma unroll
    for (int kq = 0; kq < 12; kq++)
      DOT4(hq[kq], wr[4 * kq + 0], wr[4 * kq + 1], wr[4 * kq + 2], wr[4 * kq + 3]);
    // kq 12: c48 reg + c49..51 LDS
    DOT4(hq[12], wr[48],
         wlds[0 * 512 + tid], wlds[1 * 512 + tid], wlds[2 * 512 + tid]);
    // kq 13..15: LDS
    DOT4(hq[13], wlds[3 * 512 + tid], wlds[4 * 512 + tid],
         wlds[5 * 512 + tid], wlds[6 * 512 + tid]);
    DOT4(hq[14], wlds[7 * 512 + tid], wlds[8 * 512 + tid],
         wlds[9 * 512 + tid], wlds[10 * 512 + tid]);
    DOT4(hq[15], wlds[11 * 512 + tid], wlds[12 * 512 + tid],
         wlds[13 * 512 + tid], wlds[14 * 512 + tid]);

    // publish quarter partials: coalesced float4 per thread
    *(float4*)&parts[q][jb] = make_float4(a0, a1, a2, a3);
    __syncthreads();

    // finalize: thread tid owns j = tid
    float s = parts[0][tid] + parts[1][tid] + parts[2][tid] + parts[3][tid] + pxs;
    float hv = fast_tanh(s);
    rmq = fmaxf(rmq, hv);
    _Float16 hf = (_Float16)hv;
    hbuf[tid] = __builtin_bit_cast(unsigned short, hf);
    if (t == TT - 1)
      out[2 * BB + (size_t)b * HIDD + tid] = hv;
    __syncthreads();
  }

  // pooled max -> logits (rmq is per-thread for j = tid)
  {
    float q0 = rmq * W2[tid];
    float q1 = rmq * W2[HIDD + tid];
#pragma unroll
    for (int off = 32; off; off >>= 1) {
      q0 += __shfl_down(q0, off);
      q1 += __shfl_down(q1, off);
    }
    if (l == 0) { red[0][w] = q0; red[1][w] = q1; }
  }
  __syncthreads();
  if (tid < 2) {
    float s = b2[tid];
#pragma unroll
    for (int i = 0; i < 8; i++) s += red[tid][i];
    out[b * 2 + tid] = s;
  }
}

// ---------------------------------------------------------------------------
extern "C" void kernel_launch(void* const* d_in, const int* in_sizes, int n_in,
                              void* d_out, int out_size, void* d_ws, size_t ws_size,
                              hipStream_t stream)
{
  const int*   x   = (const int*)d_in[0];
  const float* emb = (const float*)d_in[1];
  const float* W1  = (const float*)d_in[2];
  const float* b1  = (const float*)d_in[3];
  const float* W2  = (const float*)d_in[4];
  const float* b2  = (const float*)d_in[5];
  float* out = (float*)d_out;
  char* ws = (char*)d_ws;

  uint4* wp = (uint4*)ws;                        // 512 KB repacked fp16 W1h
  float* px = (float*)(ws + (1 << 19));          // 64 MB
  const size_t need = (size_t)(1 << 19) + (size_t)BB * TT * HIDD * sizeof(float);
  if (ws_size < need) return;

  repack_w1h<<<128, 256, 0, stream>>>(W1, wp);
  px_mfma<<<dim3(TT * BB / 128, HIDD / 256), 256, 0, stream>>>(x, emb, W1, b1, px);
  elman_v11<<<dim3(BB), dim3(512), 0, stream>>>(wp, px, W2, b2, out);
}

// Round 14
// 761.256 us; speedup vs baseline: 1.6828x; 1.0586x over previous
//
#include <hip/hip_runtime.h>
#include <math.h>

#define TT   512
#define BB   64
#define EMBD 512
#define HIDD 512

typedef _Float16 half2v __attribute__((ext_vector_type(2)));
typedef _Float16 half8  __attribute__((ext_vector_type(8)));
typedef float    f32x4  __attribute__((ext_vector_type(4)));

__device__ __forceinline__ float fdot2(unsigned a, unsigned b, float c) {
  half2v av = __builtin_bit_cast(half2v, a);
  half2v bv = __builtin_bit_cast(half2v, b);
  return __builtin_amdgcn_fdot2(av, bv, c, false);
}

__device__ __forceinline__ float fast_tanh(float x) {
  float e = __expf(2.0f * x);
  return 1.0f - 2.0f * __builtin_amdgcn_rcpf(e + 1.0f);
}

__device__ __forceinline__ unsigned pack2(float a, float b) {
  half2v hv; hv.x = (_Float16)a; hv.y = (_Float16)b;
  return __builtin_bit_cast(unsigned, hv);
}

__device__ __forceinline__ uint4 pack8(float4 f0, float4 f1) {
  uint4 u;
  u.x = pack2(f0.x, f0.y); u.y = pack2(f0.z, f0.w);
  u.z = pack2(f1.x, f1.y); u.w = pack2(f1.z, f1.w);
  return u;
}

// ---------------------------------------------------------------------------
// K0: repack fp32 W1h -> fp16 chunks for the v11/v12 wave-split-k mapping.
// elman thread tid: w=tid>>6 (q=w&3, hh=w>>2), l=tid&63.
// chunk c (0..63): jo=c&3, kq=c>>2. Covers j=256*hh+4*l+jo,
// k=128*q+8*kq..+8, packed as 4 dwords of (even,odd) fp16 pairs.
// ---------------------------------------------------------------------------
__global__ __launch_bounds__(256) void repack_w1h(
    const float* __restrict__ W1, uint4* __restrict__ wp)
{
  const int gid = blockIdx.x * 256 + threadIdx.x;   // 0..32767
  const int c   = gid >> 9;
  const int tid = gid & 511;
  const int w = tid >> 6, l = tid & 63;
  const int q = w & 3, hh = w >> 2;
  const int jo = c & 3, kq = c >> 2;
  const int j  = 256 * hh + 4 * l + jo;
  const int k0 = 128 * q + 8 * kq;
  const float* src = W1 + (size_t)j * (2 * EMBD) + EMBD + k0;
  unsigned r[4];
#pragma unroll
  for (int p = 0; p < 4; p++) r[p] = pack2(src[2 * p], src[2 * p + 1]);
  uint4 u; u.x = r[0]; u.y = r[1]; u.z = r[2]; u.w = r[3];
  wp[gid] = u;
}

// ---------------------------------------------------------------------------
// K1: px via fp16 MFMA (proven r12/r13: ~50 us, MFMA-active).
// ---------------------------------------------------------------------------
__global__ __launch_bounds__(256, 1) void px_mfma(
    const int* __restrict__ xx, const float* __restrict__ emb,
    const float* __restrict__ W1, const float* __restrict__ b1,
    float* __restrict__ px)
{
  __shared__ uint4 At[128 * 16];     // 32 KB: 128 rows x 256B (16 slots)
  __shared__ uint4 Bt[256 * 16];     // 64 KB: 256 rows x 256B
  __shared__ int stok[128];

  const int tid = threadIdx.x;
  const int wv  = tid >> 6, l = tid & 63;
  const int m0  = blockIdx.x * 128;
  const int j0  = blockIdx.y * 256;

  if (tid < 128) stok[tid] = xx[m0 + tid];

  f32x4 acc[8][4];
#pragma unroll
  for (int q = 0; q < 4; q++) {
    const float bc = b1[j0 + wv * 64 + 16 * q + (l & 15)];
#pragma unroll
    for (int i = 0; i < 8; i++) { acc[i][q].x = bc; acc[i][q].y = bc; acc[i][q].z = bc; acc[i][q].w = bc; }
  }

  for (int kc = 0; kc < 4; kc++) {
    __syncthreads();
    {
      const int r = tid >> 1, h = tid & 1;
      const float4* s4 = (const float4*)(emb + (size_t)stok[r] * EMBD + kc * 128 + h * 64);
#pragma unroll
      for (int i = 0; i < 8; i++)
        At[r * 16 + ((8 * h + i) ^ (r & 15))] = pack8(s4[2 * i], s4[2 * i + 1]);
      const float4* t4 = (const float4*)(W1 + (size_t)(j0 + tid) * (2 * EMBD) + kc * 128);
#pragma unroll
      for (int i = 0; i < 16; i++)
        Bt[tid * 16 + (i ^ (tid & 15))] = pack8(t4[2 * i], t4[2 * i + 1]);
    }
    __syncthreads();

#pragma unroll
    for (int ks = 0; ks < 4; ks++) {
      const int so = ks * 4 + (l >> 4);
      half8 a[8], bfr[4];
#pragma unroll
      for (int i = 0; i < 8; i++) {
        const int ra = 16 * i + (l & 15);
        a[i] = __builtin_bit_cast(half8, At[ra * 16 + (so ^ (ra & 15))]);
      }
#pragma unroll
      for (int q = 0; q < 4; q++) {
        const int rb = wv * 64 + 16 * q + (l & 15);
        bfr[q] = __builtin_bit_cast(half8, Bt[rb * 16 + (so ^ (rb & 15))]);
      }
#pragma unroll
      for (int i = 0; i < 8; i++)
#pragma unroll
        for (int q = 0; q < 4; q++)
          acc[i][q] = __builtin_amdgcn_mfma_f32_16x16x32_f16(a[i], bfr[q], acc[i][q], 0, 0, 0);
    }
  }

#pragma unroll
  for (int i = 0; i < 8; i++) {
    const int mrow = m0 + 16 * i + (l >> 4) * 4;
#pragma unroll
    for (int q = 0; q < 4; q++) {
      const int col = j0 + wv * 64 + 16 * q + (l & 15);
      float* dst = px + (size_t)mrow * HIDD + col;
      dst[0 * HIDD] = acc[i][q].x;
      dst[1 * HIDD] = acc[i][q].y;
      dst[2 * HIDD] = acc[i][q].z;
      dst[3 * HIDD] = acc[i][q].w;
    }
  }
}

// ---------------------------------------------------------------------------
// K2: recurrence v12 = v11 (r13, proven: 745 us, 0 bank conflicts) +
//   (a) amdgpu_num_vgpr(256): grant the full 2-wave arch-VGPR budget so
//       all 49 weight chunks live in true VGPRs (no AGPR round-trips);
//   (b) kq15 LDS chunks prefetched at step top (consumed last).
// Mapping unchanged: wave w: k-quarter q=w&3, j-half hh=w>>2; lane l:
// j=256*hh+4*l+{0..3}; h reads wave-uniform broadcasts; parts merge;
// linear b16 h store; two barriers/step.
// ---------------------------------------------------------------------------
#define DOT4(HH, W0, W1v, W2v, W3v) do {                                    \
    const uint4 hh = (HH);                                                  \
    a0=fdot2((W0).x,hh.x,a0);  a0=fdot2((W0).y,hh.y,a0);                    \
    a0=fdot2((W0).z,hh.z,a0);  a0=fdot2((W0).w,hh.w,a0);                    \
    a1=fdot2((W1v).x,hh.x,a1); a1=fdot2((W1v).y,hh.y,a1);                   \
    a1=fdot2((W1v).z,hh.z,a1); a1=fdot2((W1v).w,hh.w,a1);                   \
    a2=fdot2((W2v).x,hh.x,a2); a2=fdot2((W2v).y,hh.y,a2);                   \
    a2=fdot2((W2v).z,hh.z,a2); a2=fdot2((W2v).w,hh.w,a2);                   \
    a3=fdot2((W3v).x,hh.x,a3); a3=fdot2((W3v).y,hh.y,a3);                   \
    a3=fdot2((W3v).z,hh.z,a3); a3=fdot2((W3v).w,hh.w,a3);                   \
  } while (0)

__attribute__((amdgpu_flat_work_group_size(512, 512),
               amdgpu_waves_per_eu(2), amdgpu_num_vgpr(256)))
__global__ void elman_v12(
    const uint4* __restrict__ wp, const float* __restrict__ px,
    const float* __restrict__ W2, const float* __restrict__ b2,
    float* __restrict__ out)
{
  __shared__ uint4 wlds[15 * 512];          // 120 KB static (c 49..63)
  __shared__ __align__(16) unsigned short hbuf[HIDD];   // 1 KB fp16 h
  __shared__ float parts[4][HIDD];          // 8 KB quarter partials
  __shared__ float red[2][8];

  const int b   = blockIdx.x;
  const int tid = threadIdx.x;
  const int w   = tid >> 6, l = tid & 63;
  const int q   = w & 3;                    // this wave's k-quarter
  const int hh  = w >> 2;                   // this wave's j-half
  const int jb  = 256 * hh + 4 * l;         // first of this thread's 4 j

  // prologue: 49 reg chunks + 15 LDS chunks (all coalesced)
  uint4 wr[49];
#pragma unroll
  for (int i = 0; i < 49; i++) wr[i] = wp[(size_t)i * 512 + tid];
#pragma unroll
  for (int i = 0; i < 15; i++) wlds[i * 512 + tid] = wp[(size_t)(49 + i) * 512 + tid];
  if (tid < 64) ((uint4*)hbuf)[tid] = make_uint4(0u, 0u, 0u, 0u);
  __syncthreads();

  const uint4* hq = (const uint4*)hbuf + 16 * q;   // wave-uniform base
  const float* pxj = px + (size_t)b * TT * HIDD + tid;
  float rmq = -INFINITY;

  for (int t = 0; t < TT; t++) {
    // early issues: this thread's px + the kq15 LDS chunks (consumed last)
    float pxs = pxj[(size_t)t * HIDD];
    const uint4 p0 = wlds[11 * 512 + tid];
    const uint4 p1 = wlds[12 * 512 + tid];
    const uint4 p2 = wlds[13 * 512 + tid];
    const uint4 p3 = wlds[14 * 512 + tid];

    float a0 = 0.f, a1 = 0.f, a2 = 0.f, a3 = 0.f;

    // kq 0..11: register weights (h reads are wave-uniform broadcasts)
#pragma unroll
    for (int kq = 0; kq < 12; kq++)
      DOT4(hq[kq], wr[4 * kq + 0], wr[4 * kq + 1], wr[4 * kq + 2], wr[4 * kq + 3]);
    // kq 12: c48 reg + c49..51 LDS
    DOT4(hq[12], wr[48],
         wlds[0 * 512 + tid], wlds[1 * 512 + tid], wlds[2 * 512 + tid]);
    // kq 13..14: LDS
    DOT4(hq[13], wlds[3 * 512 + tid], wlds[4 * 512 + tid],
         wlds[5 * 512 + tid], wlds[6 * 512 + tid]);
    DOT4(hq[14], wlds[7 * 512 + tid], wlds[8 * 512 + tid],
         wlds[9 * 512 + tid], wlds[10 * 512 + tid]);
    // kq 15: prefetched at step top
    DOT4(hq[15], p0, p1, p2, p3);

    // publish quarter partials: coalesced float4 per thread
    *(float4*)&parts[q][jb] = make_float4(a0, a1, a2, a3);
    __syncthreads();

    // finalize: thread tid owns j = tid
    float s = parts[0][tid] + parts[1][tid] + parts[2][tid] + parts[3][tid] + pxs;
    float hv = fast_tanh(s);
    rmq = fmaxf(rmq, hv);
    _Float16 hf = (_Float16)hv;
    hbuf[tid] = __builtin_bit_cast(unsigned short, hf);
    if (t == TT - 1)
      out[2 * BB + (size_t)b * HIDD + tid] = hv;
    __syncthreads();
  }

  // pooled max -> logits (rmq is per-thread for j = tid)
  {
    float q0 = rmq * W2[tid];
    float q1 = rmq * W2[HIDD + tid];
#pragma unroll
    for (int off = 32; off; off >>= 1) {
      q0 += __shfl_down(q0, off);
      q1 += __shfl_down(q1, off);
    }
    if (l == 0) { red[0][w] = q0; red[1][w] = q1; }
  }
  __syncthreads();
  if (tid < 2) {
    float s = b2[tid];
#pragma unroll
    for (int i = 0; i < 8; i++) s += red[tid][i];
    out[b * 2 + tid] = s;
  }
}

// ---------------------------------------------------------------------------
extern "C" void kernel_launch(void* const* d_in, const int* in_sizes, int n_in,
                              void* d_out, int out_size, void* d_ws, size_t ws_size,
                              hipStream_t stream)
{
  const int*   x   = (const int*)d_in[0];
  const float* emb = (const float*)d_in[1];
  const float* W1  = (const float*)d_in[2];
  const float* b1  = (const float*)d_in[3];
  const float* W2  = (const float*)d_in[4];
  const float* b2  = (const float*)d_in[5];
  float* out = (float*)d_out;
  char* ws = (char*)d_ws;

  uint4* wp = (uint4*)ws;                        // 512 KB repacked fp16 W1h
  float* px = (float*)(ws + (1 << 19));          // 64 MB
  const size_t need = (size_t)(1 << 19) + (size_t)BB * TT * HIDD * sizeof(float);
  if (ws_size < need) return;

  repack_w1h<<<128, 256, 0, stream>>>(W1, wp);
  px_mfma<<<dim3(TT * BB / 128, HIDD / 256), 256, 0, stream>>>(x, emb, W1, b1, px);
  elman_v12<<<dim3(BB), dim3(512), 0, stream>>>(wp, px, W2, b2, out);
}